// Round 1
// baseline (27197.632 us; speedup 1.0000x reference)
//
#include <hip/hip_runtime.h>
#include <hip/hip_bf16.h>
#include <hip/hip_cooperative_groups.h>

namespace cg = cooperative_groups;

#define B_   128
#define T_   512
#define L_   8
#define E_   128
#define H_   512

// LSTM cooperative kernel partition:
#define GG_  64   // gate groups (hidden chunks of 8)
#define BG_  4    // batch groups (chunks of 32)
#define HW_  8    // hidden units per WG
#define MW_  32   // batch rows per WG
#define NW_  32   // gate rows per WG (4 gate types * HW_)
#define KW_  640  // E_ + H_
#define WPAD 648  // padded K stride for LDS W slice (16B-aligned rows, bank spread)

typedef __attribute__((ext_vector_type(8))) short s8v;    // 8 x bf16 (4 VGPRs)
typedef __attribute__((ext_vector_type(4))) float f4v;    // MFMA accumulator

// ---------------------------------------------------------------------------
// Embedding: x[t][b][e] = bf16(relu(sum_l emb[tokens[b,t,l], e] * values[b,t,l]))
// Stored time-major so each LSTM step reads a contiguous [B,E] slab.
// ---------------------------------------------------------------------------
__global__ void embed_kernel(const int* __restrict__ tokens,
                             const float* __restrict__ values,
                             const float* __restrict__ emb,
                             __hip_bfloat16* __restrict__ x_bf) {
  int idx = blockIdx.x * blockDim.x + threadIdx.x;   // [0, B*T*E)
  int e  = idx & (E_ - 1);
  int bt = idx >> 7;                                  // b*T + t
  int b  = bt >> 9;                                   // T_ = 512
  int t  = bt & (T_ - 1);
  const int*   tok = tokens + (size_t)bt * L_;
  const float* val = values + (size_t)bt * L_;
  float acc = 0.f;
#pragma unroll
  for (int l = 0; l < L_; ++l) {
    acc += emb[(size_t)tok[l] * E_ + e] * val[l];
  }
  acc = fmaxf(acc, 0.f);
  x_bf[((size_t)t * B_ + b) * E_ + e] = __float2bfloat16(acc);
}

// ---------------------------------------------------------------------------
// Persistent cooperative LSTM.
// Grid = 256 WGs x 256 threads. WG (bg, gg):
//   batch rows  [bg*32, bg*32+32)
//   hidden unit slice j0 = gg*8 .. j0+8; gate rows {g*512 + j0+jl} for g=i,f,g,o
// Per step: gates = [x_t | h_prev] @ Ws^T  via mfma_f32_16x16x32_bf16,
// then pointwise LSTM update (c in registers), h -> global double buffer,
// out partial via atomicAdd. grid.sync() between steps.
// ---------------------------------------------------------------------------
__global__ void __launch_bounds__(256, 1)
lstm_kernel(const float* __restrict__ W_ih, const float* __restrict__ W_hh,
            const float* __restrict__ b_ih, const float* __restrict__ b_hh,
            const float* __restrict__ W_out, const float* __restrict__ b_out,
            const __hip_bfloat16* __restrict__ x_bf,
            __hip_bfloat16* __restrict__ h_buf,   // 2 * B*H bf16 (zeroed)
            float* __restrict__ out) {            // B*T f32 (zeroed)
  __shared__ __align__(16) __hip_bfloat16 Ws[NW_ * WPAD];
  __shared__ float bias_s[NW_];
  __shared__ float gbuf[MW_][NW_ + 1];

  cg::grid_group grid = cg::this_grid();

  const int tid = threadIdx.x;
  const int wg  = blockIdx.x;
  const int bg  = wg >> 6;          // 0..3
  const int gg  = wg & 63;          // 0..63
  const int j0  = gg * HW_;

  // ---- one-time: W slice (bf16) + bias into LDS -------------------------
  for (int i = tid; i < NW_ * KW_; i += 256) {
    int n = i / KW_;
    int k = i - n * KW_;
    int gtype = n >> 3;
    int jl    = n & 7;
    int r = gtype * H_ + j0 + jl;                     // global gate row
    float w = (k < E_) ? W_ih[(size_t)r * E_ + k]
                       : W_hh[(size_t)r * H_ + (k - E_)];
    Ws[n * WPAD + k] = __float2bfloat16(w);
  }
  if (tid < NW_) {
    int gtype = tid >> 3, jl = tid & 7;
    int r = gtype * H_ + j0 + jl;
    bias_s[tid] = b_ih[r] + b_hh[r];
  }
  __syncthreads();

  // ---- MFMA lane identities ---------------------------------------------
  const int wv   = tid >> 6;        // wave 0..3
  const int lane = tid & 63;
  const int Mt = wv & 1, Nt = wv >> 1;
  const int m16  = lane & 15;
  const int quad = lane >> 4;
  const int kq   = quad * 8;

  const int a_m   = Mt * 16 + m16;        // within-WG batch row for A
  const int b_row = bg * MW_ + a_m;       // global batch row for A
  const int b_n   = Nt * 16 + m16;        // within-WG gate col for B/D
  const __hip_bfloat16* WsB = &Ws[b_n * WPAD + kq];

  // ---- update-phase identities ------------------------------------------
  const int um = tid >> 3;          // 0..31 batch row (local)
  const int uj = tid & 7;           // 0..7  hidden (local)
  const int ub = bg * MW_ + um;     // global batch
  const int uh = j0 + uj;           // global hidden
  float c = 0.f;
  const float wout = W_out[uh];
  const float bout = b_out[0];

  const __hip_bfloat16* hb0 = h_buf;
  const __hip_bfloat16* hb1 = h_buf + B_ * H_;

  for (int t = 0; t < T_; ++t) {
    const __hip_bfloat16* h_prev = (t & 1) ? hb1 : hb0;
    __hip_bfloat16*       h_next = (__hip_bfloat16*)((t & 1) ? hb0 : hb1);
    const __hip_bfloat16* xt     = x_bf + (size_t)t * B_ * E_;

    f4v acc = {0.f, 0.f, 0.f, 0.f};
    const __hip_bfloat16* aX = xt + (size_t)b_row * E_ + kq;
    const __hip_bfloat16* aH = h_prev + (size_t)b_row * H_ + kq;
#pragma unroll
    for (int ks = 0; ks < 4; ++ks) {                  // K over x (E=128)
      s8v a = *(const s8v*)(aX + ks * 32);
      s8v b = *(const s8v*)(WsB + ks * 32);
      acc = __builtin_amdgcn_mfma_f32_16x16x32_bf16(a, b, acc, 0, 0, 0);
    }
#pragma unroll
    for (int ks = 0; ks < 16; ++ks) {                 // K over h (H=512)
      s8v a = *(const s8v*)(aH + ks * 32);
      s8v b = *(const s8v*)(WsB + E_ + ks * 32);
      acc = __builtin_amdgcn_mfma_f32_16x16x32_bf16(a, b, acc, 0, 0, 0);
    }
    // stage gates to LDS: D row = quad*4+r, col = lane&15
#pragma unroll
    for (int r = 0; r < 4; ++r) {
      gbuf[Mt * 16 + quad * 4 + r][b_n] = acc[r];
    }
    __syncthreads();

    // pointwise LSTM update: thread (um, uj)
    {
      float gi = gbuf[um][uj]      + bias_s[uj];
      float gf = gbuf[um][8 + uj]  + bias_s[8 + uj];
      float gc = gbuf[um][16 + uj] + bias_s[16 + uj];
      float go = gbuf[um][24 + uj] + bias_s[24 + uj];
      float si = 1.f / (1.f + __expf(-gi));
      float sf = 1.f / (1.f + __expf(-gf));
      float so = 1.f / (1.f + __expf(-go));
      c = sf * c + si * tanhf(gc);
      float h = so * tanhf(c);
      h_next[(size_t)ub * H_ + uh] = __float2bfloat16(h);
      float p = wout * h;
      p += __shfl_down(p, 4, 8);
      p += __shfl_down(p, 2, 8);
      p += __shfl_down(p, 1, 8);
      if (uj == 0) {
        if (gg == 0) p += bout;
        atomicAdd(&out[(size_t)ub * T_ + t], p);
      }
    }
    __threadfence();   // make h_next stores device-visible before barrier
    grid.sync();       // step boundary (also orders gbuf reuse)
  }
}

// ---------------------------------------------------------------------------
extern "C" void kernel_launch(void* const* d_in, const int* in_sizes, int n_in,
                              void* d_out, int out_size, void* d_ws, size_t ws_size,
                              hipStream_t stream) {
  const int*   tokens = (const int*)d_in[0];
  const float* values = (const float*)d_in[1];
  const float* emb    = (const float*)d_in[2];
  const float* W_ih   = (const float*)d_in[3];
  const float* W_hh   = (const float*)d_in[4];
  const float* b_ih   = (const float*)d_in[5];
  const float* b_hh   = (const float*)d_in[6];
  const float* W_out  = (const float*)d_in[7];
  const float* b_out  = (const float*)d_in[8];
  float* out = (float*)d_out;

  char* ws = (char*)d_ws;
  __hip_bfloat16* x_bf  = (__hip_bfloat16*)ws;                              // T*B*E bf16 = 16 MB
  __hip_bfloat16* h_buf = (__hip_bfloat16*)(ws + (size_t)T_ * B_ * E_ * 2); // 2*B*H bf16

  hipMemsetAsync(h_buf, 0, (size_t)2 * B_ * H_ * sizeof(__hip_bfloat16), stream);
  hipMemsetAsync(out, 0, (size_t)B_ * T_ * sizeof(float), stream);

  embed_kernel<<<(B_ * T_ * E_) / 256, 256, 0, stream>>>(tokens, values, emb, x_bf);

  void* args[] = { (void*)&W_ih, (void*)&W_hh, (void*)&b_ih, (void*)&b_hh,
                   (void*)&W_out, (void*)&b_out, (void*)&x_bf, (void*)&h_buf,
                   (void*)&out };
  hipLaunchCooperativeKernel((void*)lstm_kernel, dim3(GG_ * BG_), dim3(256),
                             args, 0, stream);
}

// Round 2
// 6911.098 us; speedup vs baseline: 3.9354x; 3.9354x over previous
//
#include <hip/hip_runtime.h>
#include <hip/hip_bf16.h>

#define B_   128
#define T_   512
#define L_   8
#define E_   128
#define H_   512

// LSTM cooperative kernel partition:
#define GG_  64   // gate groups (hidden chunks of 8)
#define BG_  4    // batch groups (chunks of 32) -- independent barrier domains
#define HW_  8    // hidden units per WG
#define MW_  32   // batch rows per WG
#define NW_  32   // gate rows per WG (4 gate types * HW_)
#define KW_  640  // E_ + H_
#define WPAD 648  // padded K stride for LDS W slice (16B-aligned rows)

typedef __attribute__((ext_vector_type(8))) short s8v;    // 8 x bf16 (4 VGPRs)
typedef __attribute__((ext_vector_type(4))) float f4v;    // MFMA accumulator

// ---------------------------------------------------------------------------
// Embedding: x[t][b][e] = bf16(relu(sum_l emb[tokens[b,t,l], e] * values[b,t,l]))
// ---------------------------------------------------------------------------
__global__ void embed_kernel(const int* __restrict__ tokens,
                             const float* __restrict__ values,
                             const float* __restrict__ emb,
                             __hip_bfloat16* __restrict__ x_bf) {
  int idx = blockIdx.x * blockDim.x + threadIdx.x;   // [0, B*T*E)
  int e  = idx & (E_ - 1);
  int bt = idx >> 7;                                  // b*T + t
  int b  = bt >> 9;                                   // T_ = 512
  int t  = bt & (T_ - 1);
  const int*   tok = tokens + (size_t)bt * L_;
  const float* val = values + (size_t)bt * L_;
  float acc = 0.f;
#pragma unroll
  for (int l = 0; l < L_; ++l) {
    acc += emb[(size_t)tok[l] * E_ + e] * val[l];
  }
  acc = fmaxf(acc, 0.f);
  x_bf[((size_t)t * B_ + b) * E_ + e] = __float2bfloat16(acc);
}

// ---------------------------------------------------------------------------
// Hand-rolled group barrier: monotonic counter per bg group (64 WGs each).
// Arrive: RELEASE fetch_add (flushes this XCD's L2 so h stores are LLC-
// visible). Wait: relaxed agent-scope polls (LLC reads) with s_sleep backoff,
// then one acquire fence (__threadfence) to invalidate stale cached h.
// ---------------------------------------------------------------------------
__device__ __forceinline__ void group_barrier(unsigned* cnt, unsigned target) {
  __syncthreads();   // all waves drain their h stores (waitcnt vmcnt(0)) first
  if (threadIdx.x == 0) {
    __hip_atomic_fetch_add(cnt, 1u, __ATOMIC_RELEASE, __HIP_MEMORY_SCOPE_AGENT);
    while (__hip_atomic_load(cnt, __ATOMIC_RELAXED, __HIP_MEMORY_SCOPE_AGENT) < target) {
      __builtin_amdgcn_s_sleep(1);
    }
    __threadfence();  // acquire: invalidate stale lines before consuming h
  }
  __syncthreads();
}

// ---------------------------------------------------------------------------
// out[b, t] = W_out . h_t + b_out, computed by the gg==0 WG of each bg from
// the already-synchronized h buffer. Plain stores, no atomics.
// thread (um = tid>>3, uj = tid&7): 64-elem partial dot + 8-wide shfl reduce.
// ---------------------------------------------------------------------------
__device__ __forceinline__ void out_dot(const __hip_bfloat16* __restrict__ h,
                                        int t, int bg,
                                        const float* __restrict__ wout_s,
                                        float bout, float* __restrict__ out) {
  const int um = threadIdx.x >> 3;   // 0..31 local batch row
  const int uj = threadIdx.x & 7;    // 0..7  K-slice
  const int b  = bg * MW_ + um;
  const __hip_bfloat16* hr = h + (size_t)b * H_ + uj * 64;
  const float* wr = wout_s + uj * 64;
  float p = 0.f;
#pragma unroll
  for (int k = 0; k < 64; ++k) {
    p += __bfloat162float(hr[k]) * wr[k];
  }
  p += __shfl_down(p, 4, 8);
  p += __shfl_down(p, 2, 8);
  p += __shfl_down(p, 1, 8);
  if (uj == 0) out[(size_t)b * T_ + t] = p + bout;
}

// ---------------------------------------------------------------------------
// Persistent LSTM. Grid = 256 WGs x 256 threads. WG (bg, gg):
//   batch rows [bg*32, bg*32+32), hidden slice j0 = gg*8 .. +8
// Per step: gates = [x_t | h_prev] @ Ws^T via mfma_f32_16x16x32_bf16,
// pointwise update (c in regs), h -> global double buffer, group barrier.
// ---------------------------------------------------------------------------
__global__ void __launch_bounds__(256, 1)
lstm_kernel(const float* __restrict__ W_ih, const float* __restrict__ W_hh,
            const float* __restrict__ b_ih, const float* __restrict__ b_hh,
            const float* __restrict__ W_out, const float* __restrict__ b_out,
            const __hip_bfloat16* __restrict__ x_bf,
            __hip_bfloat16* __restrict__ h_buf,   // 2 * B*H bf16 (zeroed)
            float* __restrict__ out,              // B*T f32
            unsigned* __restrict__ bars) {        // BG_ counters, 128B apart
  __shared__ __align__(16) __hip_bfloat16 Ws[NW_ * WPAD];
  __shared__ float bias_s[NW_];
  __shared__ float wout_s[H_];
  __shared__ float gbuf[MW_][NW_ + 1];

  const int tid = threadIdx.x;
  const int wg  = blockIdx.x;
  const int bg  = wg >> 6;          // 0..3
  const int gg  = wg & 63;          // 0..63
  const int j0  = gg * HW_;

  // ---- one-time: W slice (bf16) + bias + W_out into LDS -----------------
  for (int i = tid; i < NW_ * KW_; i += 256) {
    int n = i / KW_;
    int k = i - n * KW_;
    int gtype = n >> 3;
    int jl    = n & 7;
    int r = gtype * H_ + j0 + jl;                     // global gate row
    float w = (k < E_) ? W_ih[(size_t)r * E_ + k]
                       : W_hh[(size_t)r * H_ + (k - E_)];
    Ws[n * WPAD + k] = __float2bfloat16(w);
  }
  if (tid < NW_) {
    int gtype = tid >> 3, jl = tid & 7;
    int r = gtype * H_ + j0 + jl;
    bias_s[tid] = b_ih[r] + b_hh[r];
  }
  for (int i = tid; i < H_; i += 256) wout_s[i] = W_out[i];
  __syncthreads();

  // ---- MFMA lane identities ---------------------------------------------
  const int wv   = tid >> 6;        // wave 0..3
  const int lane = tid & 63;
  const int Mt = wv & 1, Nt = wv >> 1;
  const int m16  = lane & 15;
  const int quad = lane >> 4;
  const int kq   = quad * 8;

  const int a_m   = Mt * 16 + m16;        // within-WG batch row for A
  const int b_row = bg * MW_ + a_m;       // global batch row for A
  const int b_n   = Nt * 16 + m16;        // within-WG gate col for B/D
  const __hip_bfloat16* WsB = &Ws[b_n * WPAD + kq];

  // ---- update-phase identities ------------------------------------------
  const int um = tid >> 3;          // 0..31 batch row (local)
  const int uj = tid & 7;           // 0..7  hidden (local)
  const int ub = bg * MW_ + um;     // global batch
  const int uh = j0 + uj;           // global hidden
  float c = 0.f;
  const float bout = b_out[0];

  const __hip_bfloat16* hb0 = h_buf;
  const __hip_bfloat16* hb1 = h_buf + B_ * H_;
  unsigned* cnt = bars + bg * 32;   // one 128B cache line per bg group

  for (int t = 0; t < T_; ++t) {
    const __hip_bfloat16* h_prev = (t & 1) ? hb1 : hb0;
    __hip_bfloat16*       h_next = (__hip_bfloat16*)((t & 1) ? hb0 : hb1);
    const __hip_bfloat16* xt     = x_bf + (size_t)t * B_ * E_;

    f4v acc = {0.f, 0.f, 0.f, 0.f};
    const __hip_bfloat16* aX = xt + (size_t)b_row * E_ + kq;
    const __hip_bfloat16* aH = h_prev + (size_t)b_row * H_ + kq;
#pragma unroll
    for (int ks = 0; ks < 4; ++ks) {                  // K over x (E=128)
      s8v a = *(const s8v*)(aX + ks * 32);
      s8v b = *(const s8v*)(WsB + ks * 32);
      acc = __builtin_amdgcn_mfma_f32_16x16x32_bf16(a, b, acc, 0, 0, 0);
    }
#pragma unroll
    for (int ks = 0; ks < 16; ++ks) {                 // K over h (H=512)
      s8v a = *(const s8v*)(aH + ks * 32);
      s8v b = *(const s8v*)(WsB + E_ + ks * 32);
      acc = __builtin_amdgcn_mfma_f32_16x16x32_bf16(a, b, acc, 0, 0, 0);
    }
    // stage gates to LDS: D row = quad*4+r, col = lane&15
#pragma unroll
    for (int r = 0; r < 4; ++r) {
      gbuf[Mt * 16 + quad * 4 + r][b_n] = acc[r];
    }
    __syncthreads();

    // pointwise LSTM update: thread (um, uj)
    {
      float gi = gbuf[um][uj]      + bias_s[uj];
      float gf = gbuf[um][8 + uj]  + bias_s[8 + uj];
      float gc = gbuf[um][16 + uj] + bias_s[16 + uj];
      float go = gbuf[um][24 + uj] + bias_s[24 + uj];
      float si = 1.f / (1.f + __expf(-gi));
      float sf = 1.f / (1.f + __expf(-gf));
      float so = 1.f / (1.f + __expf(-go));
      c = sf * c + si * tanhf(gc);
      float h = so * tanhf(c);
      h_next[(size_t)ub * H_ + uh] = __float2bfloat16(h);
    }

    // out[.., t-1] from h_prev (already globally synchronized) — no atomics
    if (gg == 0 && t > 0) {
      out_dot(h_prev, t - 1, bg, wout_s, bout, out);
    }

    group_barrier(cnt, (unsigned)(t + 1) * GG_);
  }

  // final h (t=511, odd) lives in hb0; last in-loop barrier ordered it
  if (gg == 0) {
    out_dot(hb0, T_ - 1, bg, wout_s, bout, out);
  }
}

// ---------------------------------------------------------------------------
extern "C" void kernel_launch(void* const* d_in, const int* in_sizes, int n_in,
                              void* d_out, int out_size, void* d_ws, size_t ws_size,
                              hipStream_t stream) {
  const int*   tokens = (const int*)d_in[0];
  const float* values = (const float*)d_in[1];
  const float* emb    = (const float*)d_in[2];
  const float* W_ih   = (const float*)d_in[3];
  const float* W_hh   = (const float*)d_in[4];
  const float* b_ih   = (const float*)d_in[5];
  const float* b_hh   = (const float*)d_in[6];
  const float* W_out  = (const float*)d_in[7];
  const float* b_out  = (const float*)d_in[8];
  float* out = (float*)d_out;

  char* ws = (char*)d_ws;
  __hip_bfloat16* x_bf  = (__hip_bfloat16*)ws;                              // T*B*E bf16 = 16 MB
  __hip_bfloat16* h_buf = (__hip_bfloat16*)(ws + (size_t)T_ * B_ * E_ * 2); // 2*B*H bf16
  unsigned* bars = (unsigned*)(ws + (size_t)T_ * B_ * E_ * 2
                                  + (size_t)2 * B_ * H_ * 2);               // BG_ x 128B

  hipMemsetAsync(h_buf, 0, (size_t)2 * B_ * H_ * sizeof(__hip_bfloat16), stream);
  hipMemsetAsync(bars, 0, (size_t)BG_ * 32 * sizeof(unsigned), stream);

  embed_kernel<<<(B_ * T_ * E_) / 256, 256, 0, stream>>>(tokens, values, emb, x_bf);

  void* args[] = { (void*)&W_ih, (void*)&W_hh, (void*)&b_ih, (void*)&b_hh,
                   (void*)&W_out, (void*)&b_out, (void*)&x_bf, (void*)&h_buf,
                   (void*)&out, (void*)&bars };
  hipLaunchCooperativeKernel((void*)lstm_kernel, dim3(GG_ * BG_), dim3(256),
                             args, 0, stream);
}

// Round 3
// 3935.996 us; speedup vs baseline: 6.9100x; 1.7559x over previous
//
#include <hip/hip_runtime.h>
#include <hip/hip_bf16.h>

#define B_   128
#define T_   512
#define L_   8
#define E_   128
#define H_   512

// LSTM cooperative kernel partition:
#define GG_  64   // gate groups (hidden chunks of 8)
#define BG_  4    // batch groups (chunks of 32) -- independent barrier domains
#define HW_  8    // hidden units per WG
#define MW_  32   // batch rows per WG
#define NW_  32   // gate rows per WG (4 gate types * HW_)
#define KW_  640  // E_ + H_
#define WPAD 648  // padded K stride for LDS W slice (16B-aligned rows)

typedef __attribute__((ext_vector_type(8))) short s8v;    // 8 x bf16 (4 VGPRs)
typedef __attribute__((ext_vector_type(4))) float f4v;    // MFMA accumulator

typedef union { unsigned long long q[2]; s8v v; } frag_u;

__device__ __forceinline__ float bf16u_to_f(unsigned short s) {
  union { unsigned u; float f; } c; c.u = ((unsigned)s) << 16; return c.f;
}

// LLC-coherent (sc1) 8-byte load: bypasses the (possibly stale) per-XCD L2.
__device__ __forceinline__ unsigned long long llc_load8(const void* p) {
  return __hip_atomic_load((const unsigned long long*)p,
                           __ATOMIC_RELAXED, __HIP_MEMORY_SCOPE_AGENT);
}

// ---------------------------------------------------------------------------
// Embedding: x[t][b][e] = bf16(relu(sum_l emb[tokens[b,t,l], e] * values[b,t,l]))
// ---------------------------------------------------------------------------
__global__ void embed_kernel(const int* __restrict__ tokens,
                             const float* __restrict__ values,
                             const float* __restrict__ emb,
                             __hip_bfloat16* __restrict__ x_bf) {
  int idx = blockIdx.x * blockDim.x + threadIdx.x;   // [0, B*T*E)
  int e  = idx & (E_ - 1);
  int bt = idx >> 7;                                  // b*T + t
  int b  = bt >> 9;                                   // T_ = 512
  int t  = bt & (T_ - 1);
  const int*   tok = tokens + (size_t)bt * L_;
  const float* val = values + (size_t)bt * L_;
  float acc = 0.f;
#pragma unroll
  for (int l = 0; l < L_; ++l) {
    acc += emb[(size_t)tok[l] * E_ + e] * val[l];
  }
  acc = fmaxf(acc, 0.f);
  x_bf[((size_t)t * B_ + b) * E_ + e] = __float2bfloat16(acc);
}

// ---------------------------------------------------------------------------
// Fence-free group barrier. All cross-WG data (h) moves via sc1 LLC-coherent
// accesses, so no L2 writeback/invalidate is needed. Ordering: __syncthreads
// drains vmcnt(0); sc1 stores complete at the LLC, so the (relaxed, LLC)
// counter add is LLC-ordered after the h data.
// ---------------------------------------------------------------------------
__device__ __forceinline__ void group_barrier(unsigned* cnt, unsigned target) {
  __syncthreads();   // drain h stores (vmcnt(0)) + compiler barrier
  if (threadIdx.x == 0) {
    __hip_atomic_fetch_add(cnt, 1u, __ATOMIC_RELAXED, __HIP_MEMORY_SCOPE_AGENT);
    while (__hip_atomic_load(cnt, __ATOMIC_RELAXED, __HIP_MEMORY_SCOPE_AGENT) < target) {
      __builtin_amdgcn_s_sleep(2);
    }
  }
  __syncthreads();
}

// ---------------------------------------------------------------------------
// out[b, t] = W_out . h_t + b_out (gg==0 WG of each bg). h read via sc1 loads.
// thread (um = tid>>3, uj = tid&7): 64-elem partial dot + 8-wide shfl reduce.
// ---------------------------------------------------------------------------
__device__ __forceinline__ void out_dot(const __hip_bfloat16* __restrict__ h,
                                        int t, int bg,
                                        const float* __restrict__ wout_s,
                                        float bout, float* __restrict__ out) {
  const int um = threadIdx.x >> 3;   // 0..31 local batch row
  const int uj = threadIdx.x & 7;    // 0..7  K-slice
  const int b  = bg * MW_ + um;
  const __hip_bfloat16* hr = h + (size_t)b * H_ + uj * 64;
  const float* wr = wout_s + uj * 64;
  float p = 0.f;
#pragma unroll
  for (int kk = 0; kk < 16; ++kk) {
    unsigned long long q = llc_load8(hr + kk * 4);
    p += bf16u_to_f((unsigned short)(q      )) * wr[kk * 4 + 0];
    p += bf16u_to_f((unsigned short)(q >> 16)) * wr[kk * 4 + 1];
    p += bf16u_to_f((unsigned short)(q >> 32)) * wr[kk * 4 + 2];
    p += bf16u_to_f((unsigned short)(q >> 48)) * wr[kk * 4 + 3];
  }
  p += __shfl_down(p, 4, 8);
  p += __shfl_down(p, 2, 8);
  p += __shfl_down(p, 1, 8);
  if (uj == 0) out[(size_t)b * T_ + t] = p + bout;
}

// ---------------------------------------------------------------------------
// Persistent LSTM. Grid = 256 WGs x 256 threads. WG (bg, gg):
//   batch rows [bg*32, bg*32+32), hidden slice j0 = gg*8 .. +8
// Per step: gates = [x_t | h_prev] @ Ws^T via mfma_f32_16x16x32_bf16,
// pointwise update (c in regs, 2 units/thread), h -> LLC via sc1 stores,
// fence-free group barrier.
// ---------------------------------------------------------------------------
__global__ void __launch_bounds__(256, 1)
lstm_kernel(const float* __restrict__ W_ih, const float* __restrict__ W_hh,
            const float* __restrict__ b_ih, const float* __restrict__ b_hh,
            const float* __restrict__ W_out, const float* __restrict__ b_out,
            const __hip_bfloat16* __restrict__ x_bf,
            __hip_bfloat16* __restrict__ h_buf,   // 2 * B*H bf16 (zeroed)
            float* __restrict__ out,              // B*T f32
            unsigned* __restrict__ bars) {        // BG_ counters, 128B apart
  __shared__ __align__(16) __hip_bfloat16 Ws[NW_ * WPAD];
  __shared__ float bias_s[NW_];
  __shared__ float wout_s[H_];
  __shared__ float gbuf[MW_][NW_ + 1];

  const int tid = threadIdx.x;
  const int wg  = blockIdx.x;
  const int bg  = wg >> 6;          // 0..3
  const int gg  = wg & 63;          // 0..63
  const int j0  = gg * HW_;

  // ---- one-time: W slice (bf16) + bias + W_out into LDS -----------------
  for (int i = tid; i < NW_ * KW_; i += 256) {
    int n = i / KW_;
    int k = i - n * KW_;
    int gtype = n >> 3;
    int jl    = n & 7;
    int r = gtype * H_ + j0 + jl;                     // global gate row
    float w = (k < E_) ? W_ih[(size_t)r * E_ + k]
                       : W_hh[(size_t)r * H_ + (k - E_)];
    Ws[n * WPAD + k] = __float2bfloat16(w);
  }
  if (tid < NW_) {
    int gtype = tid >> 3, jl = tid & 7;
    int r = gtype * H_ + j0 + jl;
    bias_s[tid] = b_ih[r] + b_hh[r];
  }
  for (int i = tid; i < H_; i += 256) wout_s[i] = W_out[i];
  __syncthreads();

  // ---- MFMA lane identities ---------------------------------------------
  const int wv   = tid >> 6;        // wave 0..3
  const int lane = tid & 63;
  const int Mt = wv & 1, Nt = wv >> 1;
  const int m16  = lane & 15;
  const int quad = lane >> 4;
  const int kq   = quad * 8;

  const int a_m   = Mt * 16 + m16;        // within-WG batch row for A
  const int b_row = bg * MW_ + a_m;       // global batch row for A
  const int b_n   = Nt * 16 + m16;        // within-WG gate col for B/D
  const __hip_bfloat16* WsB = &Ws[b_n * WPAD + kq];

  // ---- update-phase identities (2 hidden units per thread, tid<128) -----
  const int um  = tid >> 2;         // 0..31 batch row (local)    [tid<128]
  const int ujp = tid & 3;          // 0..3  hidden-pair index
  const int jl0 = ujp * 2, jl1 = jl0 + 1;
  const int ub  = bg * MW_ + um;    // global batch
  const int uh  = j0 + jl0;         // global hidden (even)
  float c0 = 0.f, c1 = 0.f;
  const float bout = b_out[0];

  const __hip_bfloat16* hb0 = h_buf;
  const __hip_bfloat16* hb1 = h_buf + B_ * H_;
  unsigned* cnt = bars + bg * 32;   // one 128B cache line per bg group

  for (int t = 0; t < T_; ++t) {
    const __hip_bfloat16* h_prev = (t & 1) ? hb1 : hb0;
    __hip_bfloat16*       h_next = (__hip_bfloat16*)((t & 1) ? hb0 : hb1);
    const __hip_bfloat16* xt     = x_bf + (size_t)t * B_ * E_;

    f4v acc = {0.f, 0.f, 0.f, 0.f};
    const __hip_bfloat16* aX = xt + (size_t)b_row * E_ + kq;
    const __hip_bfloat16* aH = h_prev + (size_t)b_row * H_ + kq;
#pragma unroll
    for (int ks = 0; ks < 4; ++ks) {                  // K over x (E=128)
      s8v a = *(const s8v*)(aX + ks * 32);
      s8v b = *(const s8v*)(WsB + ks * 32);
      acc = __builtin_amdgcn_mfma_f32_16x16x32_bf16(a, b, acc, 0, 0, 0);
    }
#pragma unroll
    for (int ks = 0; ks < 16; ++ks) {                 // K over h (H=512), sc1
      frag_u a;
      a.q[0] = llc_load8(aH + ks * 32);
      a.q[1] = llc_load8(aH + ks * 32 + 4);
      s8v b = *(const s8v*)(WsB + E_ + ks * 32);
      acc = __builtin_amdgcn_mfma_f32_16x16x32_bf16(a.v, b, acc, 0, 0, 0);
    }
    // stage gates to LDS: D row = quad*4+r, col = lane&15
#pragma unroll
    for (int r = 0; r < 4; ++r) {
      gbuf[Mt * 16 + quad * 4 + r][b_n] = acc[r];
    }
    __syncthreads();

    // pointwise LSTM update: thread (um, pair jl0/jl1), tid < 128
    if (tid < 128) {
      float gi0 = gbuf[um][jl0]      + bias_s[jl0];
      float gf0 = gbuf[um][8 + jl0]  + bias_s[8 + jl0];
      float gc0 = gbuf[um][16 + jl0] + bias_s[16 + jl0];
      float go0 = gbuf[um][24 + jl0] + bias_s[24 + jl0];
      float gi1 = gbuf[um][jl1]      + bias_s[jl1];
      float gf1 = gbuf[um][8 + jl1]  + bias_s[8 + jl1];
      float gc1 = gbuf[um][16 + jl1] + bias_s[16 + jl1];
      float go1 = gbuf[um][24 + jl1] + bias_s[24 + jl1];
      float si0 = 1.f / (1.f + __expf(-gi0));
      float sf0 = 1.f / (1.f + __expf(-gf0));
      float so0 = 1.f / (1.f + __expf(-go0));
      float si1 = 1.f / (1.f + __expf(-gi1));
      float sf1 = 1.f / (1.f + __expf(-gf1));
      float so1 = 1.f / (1.f + __expf(-go1));
      c0 = sf0 * c0 + si0 * tanhf(gc0);
      c1 = sf1 * c1 + si1 * tanhf(gc1);
      float h0 = so0 * tanhf(c0);
      float h1 = so1 * tanhf(c1);
      __hip_bfloat16 h0b = __float2bfloat16(h0);
      __hip_bfloat16 h1b = __float2bfloat16(h1);
      unsigned packed = (unsigned)*(unsigned short*)&h0b
                      | ((unsigned)*(unsigned short*)&h1b << 16);
      // LLC-coherent write-through (sc1): L2 never holds dirty h lines
      __hip_atomic_store((unsigned*)&h_next[(size_t)ub * H_ + uh], packed,
                         __ATOMIC_RELAXED, __HIP_MEMORY_SCOPE_AGENT);
    }

    // out[.., t-1] from h_prev (synchronized last step) — no atomicAdd
    if (gg == 0 && t > 0) {
      out_dot(h_prev, t - 1, bg, wout_s, bout, out);
    }

    group_barrier(cnt, (unsigned)(t + 1) * GG_);
  }

  // final h (t=511, odd) lives in hb0; last in-loop barrier ordered it
  if (gg == 0) {
    out_dot(hb0, T_ - 1, bg, wout_s, bout, out);
  }
}

// ---------------------------------------------------------------------------
extern "C" void kernel_launch(void* const* d_in, const int* in_sizes, int n_in,
                              void* d_out, int out_size, void* d_ws, size_t ws_size,
                              hipStream_t stream) {
  const int*   tokens = (const int*)d_in[0];
  const float* values = (const float*)d_in[1];
  const float* emb    = (const float*)d_in[2];
  const float* W_ih   = (const float*)d_in[3];
  const float* W_hh   = (const float*)d_in[4];
  const float* b_ih   = (const float*)d_in[5];
  const float* b_hh   = (const float*)d_in[6];
  const float* W_out  = (const float*)d_in[7];
  const float* b_out  = (const float*)d_in[8];
  float* out = (float*)d_out;

  char* ws = (char*)d_ws;
  __hip_bfloat16* x_bf  = (__hip_bfloat16*)ws;                              // T*B*E bf16 = 16 MB
  __hip_bfloat16* h_buf = (__hip_bfloat16*)(ws + (size_t)T_ * B_ * E_ * 2); // 2*B*H bf16
  unsigned* bars = (unsigned*)(ws + (size_t)T_ * B_ * E_ * 2
                                  + (size_t)2 * B_ * H_ * 2);               // BG_ x 128B

  hipMemsetAsync(h_buf, 0, (size_t)2 * B_ * H_ * sizeof(__hip_bfloat16), stream);
  hipMemsetAsync(bars, 0, (size_t)BG_ * 32 * sizeof(unsigned), stream);

  embed_kernel<<<(B_ * T_ * E_) / 256, 256, 0, stream>>>(tokens, values, emb, x_bf);

  void* args[] = { (void*)&W_ih, (void*)&W_hh, (void*)&b_ih, (void*)&b_hh,
                   (void*)&W_out, (void*)&b_out, (void*)&x_bf, (void*)&h_buf,
                   (void*)&out, (void*)&bars };
  hipLaunchCooperativeKernel((void*)lstm_kernel, dim3(GG_ * BG_), dim3(256),
                             args, 0, stream);
}

// Round 5
// 2546.716 us; speedup vs baseline: 10.6795x; 1.5455x over previous
//
#include <hip/hip_runtime.h>
#include <hip/hip_bf16.h>

#define B_   128
#define T_   512
#define L_   8
#define E_   128
#define H_   512

// Partition: 4 batch-groups (32 rows each) x 16 WGs = 64 WGs, 256 thr each.
// WG (bg,g): batch rows [bg*32,+32), hidden units [g*32,+32) -> 128 gate rows.
// Wave wv = gate type; per wave N=32 (2 N-tiles), M=32 (2 M-tiles), K=640.
// W fragments live in registers (160 VGPRs/wave) -- loaded once.
// Plain launch (NOT cooperative): 64 blocks / 256 CUs, 1 block/CU at
// launch_bounds(256,1), 53KB LDS -> all resident immediately; hand-rolled
// per-bg barrier needs only that. (R4's hipLaunchCooperativeKernel appears
// to have failed validation silently -> stub behavior.)
#define BG_   4
#define WPG_  16
#define JW_   32
#define HU64_ (B_ * H_ / 4)   // u64 per h buffer (16384)

typedef __attribute__((ext_vector_type(8))) short s8v;   // 8 bf16
typedef __attribute__((ext_vector_type(4))) float f4v;   // MFMA acc
typedef unsigned long long u64;

__device__ __forceinline__ float bf16u_to_f(unsigned short s) {
  union { unsigned u; float f; } c; c.u = ((unsigned)s) << 16; return c.f;
}
// LLC-coherent (sc1) accesses: bypass non-coherent per-XCD L2.
__device__ __forceinline__ u64 llc_load8(const void* p) {
  return __hip_atomic_load((const u64*)p, __ATOMIC_RELAXED, __HIP_MEMORY_SCOPE_AGENT);
}
__device__ __forceinline__ void llc_store8(void* p, u64 v) {
  __hip_atomic_store((u64*)p, v, __ATOMIC_RELAXED, __HIP_MEMORY_SCOPE_AGENT);
}
__device__ __forceinline__ float sigf(float x) { return 1.f / (1.f + __expf(-x)); }

// ---------------------------------------------------------------------------
__global__ void embed_kernel(const int* __restrict__ tokens,
                             const float* __restrict__ values,
                             const float* __restrict__ emb,
                             __hip_bfloat16* __restrict__ x_bf) {
  int idx = blockIdx.x * blockDim.x + threadIdx.x;   // [0, B*T*E)
  int e  = idx & (E_ - 1);
  int bt = idx >> 7;
  int b  = bt >> 9;
  int t  = bt & (T_ - 1);
  const int*   tok = tokens + (size_t)bt * L_;
  const float* val = values + (size_t)bt * L_;
  float acc = 0.f;
#pragma unroll
  for (int l = 0; l < L_; ++l) acc += emb[(size_t)tok[l] * E_ + e] * val[l];
  acc = fmaxf(acc, 0.f);
  x_bf[((size_t)t * B_ + b) * E_ + e] = __float2bfloat16(acc);
}

// ---------------------------------------------------------------------------
// out[b,t] = W_out . h_t + b_out from the LDS-staged (xor-swizzled) slab.
__device__ __forceinline__ void out_dot_lds(const u64* __restrict__ h_lds,
                                            int t, int bg,
                                            const float* __restrict__ wout_s,
                                            float bout, float* __restrict__ out) {
  const int um = threadIdx.x >> 3;
  const int uj = threadIdx.x & 7;
  const u64* row = h_lds + (size_t)um * 128;
  const float* wr = wout_s + uj * 64;
  float p = 0.f;
#pragma unroll
  for (int j = 0; j < 8; ++j) {
    int pc = ((uj * 8 + j) ^ (um & 7)) * 2;
    u64 qa = row[pc], qb = row[pc + 1];
    p += bf16u_to_f((unsigned short)(qa      )) * wr[j * 8 + 0];
    p += bf16u_to_f((unsigned short)(qa >> 16)) * wr[j * 8 + 1];
    p += bf16u_to_f((unsigned short)(qa >> 32)) * wr[j * 8 + 2];
    p += bf16u_to_f((unsigned short)(qa >> 48)) * wr[j * 8 + 3];
    p += bf16u_to_f((unsigned short)(qb      )) * wr[j * 8 + 4];
    p += bf16u_to_f((unsigned short)(qb >> 16)) * wr[j * 8 + 5];
    p += bf16u_to_f((unsigned short)(qb >> 32)) * wr[j * 8 + 6];
    p += bf16u_to_f((unsigned short)(qb >> 48)) * wr[j * 8 + 7];
  }
  p += __shfl_down(p, 4, 8);
  p += __shfl_down(p, 2, 8);
  p += __shfl_down(p, 1, 8);
  if (uj == 0) out[(size_t)(bg * 32 + um) * T_ + t] = p + bout;
}

// Final-step variant: read h from global (LLC) since LDS holds h_{T-2}.
__device__ __forceinline__ void out_dot_glb(const u64* __restrict__ h,
                                            int t, int bg,
                                            const float* __restrict__ wout_s,
                                            float bout, float* __restrict__ out) {
  const int um = threadIdx.x >> 3;
  const int uj = threadIdx.x & 7;
  const int b  = bg * 32 + um;
  const u64* hr = h + (size_t)b * 128 + uj * 16;
  const float* wr = wout_s + uj * 64;
  float p = 0.f;
#pragma unroll
  for (int kk = 0; kk < 16; ++kk) {
    u64 q = llc_load8(hr + kk);
    p += bf16u_to_f((unsigned short)(q      )) * wr[kk * 4 + 0];
    p += bf16u_to_f((unsigned short)(q >> 16)) * wr[kk * 4 + 1];
    p += bf16u_to_f((unsigned short)(q >> 32)) * wr[kk * 4 + 2];
    p += bf16u_to_f((unsigned short)(q >> 48)) * wr[kk * 4 + 3];
  }
  p += __shfl_down(p, 4, 8);
  p += __shfl_down(p, 2, 8);
  p += __shfl_down(p, 1, 8);
  if (uj == 0) out[(size_t)b * T_ + t] = p + bout;
}

// ---------------------------------------------------------------------------
__global__ void __launch_bounds__(256, 1)
lstm_kernel(const float* __restrict__ W_ih, const float* __restrict__ W_hh,
            const float* __restrict__ b_ih, const float* __restrict__ b_hh,
            const float* __restrict__ W_out, const float* __restrict__ b_out,
            const __hip_bfloat16* __restrict__ x_bf,
            u64* __restrict__ h_base,             // 3 * B*H bf16 (zeroed), u64 view
            float* __restrict__ out,              // B*T f32
            unsigned* __restrict__ bars) {        // BG_ counters, 256B apart
  __shared__ u64   h_lds[32 * 128];       // 32 rows x 64 16B-chunks, xor-swizzled
  __shared__ float gbuf[32][136];         // gates staging (stride 136)
  __shared__ float bias_s[128];
  __shared__ float wout_s[H_];

  const int tid = threadIdx.x;
  const int wg  = blockIdx.x;
  const int bg  = wg >> 4;            // 0..3
  const int g   = wg & (WPG_ - 1);    // 0..15
  const int j0g = g * JW_;

  const int wv   = tid >> 6;          // wave = gate type 0..3
  const int lane = tid & 63;
  const int m16  = lane & 15;
  const int q    = lane >> 4;
  const int sw   = m16 & 7;           // xor-swizzle key (row low bits)

  // ---- one-time: W fragments -> registers (B operand, 2 N-tiles x 20 K) --
  s8v bfrag[2][20];
#pragma unroll
  for (int nt = 0; nt < 2; ++nt) {
    const int r = wv * H_ + j0g + nt * 16 + m16;        // global gate row
    const float* wih_r = W_ih + (size_t)r * E_;
    const float* whh_r = W_hh + (size_t)r * H_;
#pragma unroll
    for (int ks = 0; ks < 20; ++ks) {
      s8v v;
#pragma unroll
      for (int i = 0; i < 8; ++i) {
        int k = ks * 32 + q * 8 + i;
        float w = (k < E_) ? wih_r[k] : whh_r[k - E_];
        __hip_bfloat16 hb = __float2bfloat16(w);
        v[i] = *(short*)&hb;
      }
      bfrag[nt][ks] = v;
    }
  }
  if (tid < 128) {
    int gt = tid >> 5, jl = tid & 31;
    int r = gt * H_ + j0g + jl;
    bias_s[tid] = b_ih[r] + b_hh[r];
  }
  if (g == 0) for (int i = tid; i < H_; i += 256) wout_s[i] = W_out[i];

  // ---- per-step identities ----------------------------------------------
  const int um = tid >> 3;            // update: local batch row
  const int jb = (tid & 7) * 4;       // update: 4 hidden units
  const int ub = bg * 32 + um;
  const int fm = tid >> 3;            // fill: row
  const int fc = tid & 7;             // fill: chunk base
  float cst[4] = {0.f, 0.f, 0.f, 0.f};
  const float bout = b_out[0];
  unsigned* cnt = bars + bg * 64;     // 256B-separated per-bg counter

  int rp = 2, wp = 0;                 // h_{-1}=zeros in buf2; h_t -> buf[t%3]
  f4v acc[2][2];

  // prologue: x-part of step 0
  {
    const __hip_bfloat16* xt = x_bf;
    const __hip_bfloat16* ax0 = xt + (size_t)(bg * 32 + m16) * E_ + q * 8;
    const __hip_bfloat16* ax1 = xt + (size_t)(bg * 32 + 16 + m16) * E_ + q * 8;
    f4v z = {0.f, 0.f, 0.f, 0.f};
    acc[0][0] = z; acc[0][1] = z; acc[1][0] = z; acc[1][1] = z;
#pragma unroll
    for (int ks = 0; ks < 4; ++ks) {
      s8v a0 = *(const s8v*)(ax0 + ks * 32);
      s8v a1 = *(const s8v*)(ax1 + ks * 32);
#pragma unroll
      for (int nt = 0; nt < 2; ++nt) {
        acc[0][nt] = __builtin_amdgcn_mfma_f32_16x16x32_bf16(a0, bfrag[nt][ks], acc[0][nt], 0, 0, 0);
        acc[1][nt] = __builtin_amdgcn_mfma_f32_16x16x32_bf16(a1, bfrag[nt][ks], acc[1][nt], 0, 0, 0);
      }
    }
  }
  __syncthreads();   // bias/wout ready; also orders first h_lds fill

  for (int t = 0; t < T_; ++t) {
    const u64* h_prev = h_base + (size_t)rp * HU64_;
    u64*       h_next = h_base + (size_t)wp * HU64_;

    // ---- cooperative fill: h_prev slab -> LDS (xor-swizzled chunks) -----
    {
      const u64* src = h_prev + (size_t)(bg * 32 + fm) * 128;
      u64 v[16];
#pragma unroll
      for (int j = 0; j < 8; ++j) {
        int lc = fc + 8 * j;
        v[2 * j]     = llc_load8(src + lc * 2);
        v[2 * j + 1] = llc_load8(src + lc * 2 + 1);
      }
      u64* dst = h_lds + (size_t)fm * 128;
#pragma unroll
      for (int j = 0; j < 8; ++j) {
        int pc = ((fc + 8 * j) ^ (fm & 7)) * 2;
        dst[pc]     = v[2 * j];
        dst[pc + 1] = v[2 * j + 1];
      }
    }
    __syncthreads();

    // ---- h-part MFMAs (K=512 from LDS; B from registers) ----------------
    {
      const u64* al0 = h_lds + (size_t)m16 * 128;
      const u64* al1 = h_lds + (size_t)(16 + m16) * 128;
#pragma unroll
      for (int ks4 = 0; ks4 < 16; ++ks4) {
        int pc = ((ks4 * 4 + q) ^ sw) * 2;
        s8v a0 = *(const s8v*)(al0 + pc);
        s8v a1 = *(const s8v*)(al1 + pc);
#pragma unroll
        for (int nt = 0; nt < 2; ++nt) {
          acc[0][nt] = __builtin_amdgcn_mfma_f32_16x16x32_bf16(a0, bfrag[nt][4 + ks4], acc[0][nt], 0, 0, 0);
          acc[1][nt] = __builtin_amdgcn_mfma_f32_16x16x32_bf16(a1, bfrag[nt][4 + ks4], acc[1][nt], 0, 0, 0);
        }
      }
    }

    // ---- stage gates to LDS (D: row=quad*4+r, col=m16) ------------------
#pragma unroll
    for (int mt = 0; mt < 2; ++mt)
#pragma unroll
      for (int nt = 0; nt < 2; ++nt)
#pragma unroll
        for (int r = 0; r < 4; ++r)
          gbuf[mt * 16 + q * 4 + r][wv * 32 + nt * 16 + m16] = acc[mt][nt][r];
    __syncthreads();

    // ---- pointwise update: 4 hidden units per thread --------------------
    {
      u64 packed = 0;
#pragma unroll
      for (int qq = 0; qq < 4; ++qq) {
        int j = jb + qq;
        float gi = gbuf[um][      j] + bias_s[      j];
        float gf = gbuf[um][32  + j] + bias_s[32  + j];
        float gc = gbuf[um][64  + j] + bias_s[64  + j];
        float go = gbuf[um][96  + j] + bias_s[96  + j];
        cst[qq] = sigf(gf) * cst[qq] + sigf(gi) * tanhf(gc);
        float h = sigf(go) * tanhf(cst[qq]);
        __hip_bfloat16 hb = __float2bfloat16(h);
        packed |= (u64)(*(unsigned short*)&hb) << (16 * qq);
      }
      llc_store8(h_next + (size_t)ub * 128 + ((j0g + jb) >> 2), packed);
    }
    __syncthreads();   // drain h stores (vmcnt) before arrival

    // ---- arrive; off-critical-path work; poll ---------------------------
    if (tid == 0)
      __hip_atomic_fetch_add(cnt, 1u, __ATOMIC_RELAXED, __HIP_MEMORY_SCOPE_AGENT);

    if (g == 0 && t > 0)                      // h_{t-1} still staged in LDS
      out_dot_lds(h_lds, t - 1, bg, wout_s, bout, out);

    if (t + 1 < T_) {                         // x-part of step t+1 (overlap)
      const __hip_bfloat16* xt = x_bf + (size_t)(t + 1) * B_ * E_;
      const __hip_bfloat16* ax0 = xt + (size_t)(bg * 32 + m16) * E_ + q * 8;
      const __hip_bfloat16* ax1 = xt + (size_t)(bg * 32 + 16 + m16) * E_ + q * 8;
      f4v z = {0.f, 0.f, 0.f, 0.f};
      acc[0][0] = z; acc[0][1] = z; acc[1][0] = z; acc[1][1] = z;
#pragma unroll
      for (int ks = 0; ks < 4; ++ks) {
        s8v a0 = *(const s8v*)(ax0 + ks * 32);
        s8v a1 = *(const s8v*)(ax1 + ks * 32);
#pragma unroll
        for (int nt = 0; nt < 2; ++nt) {
          acc[0][nt] = __builtin_amdgcn_mfma_f32_16x16x32_bf16(a0, bfrag[nt][ks], acc[0][nt], 0, 0, 0);
          acc[1][nt] = __builtin_amdgcn_mfma_f32_16x16x32_bf16(a1, bfrag[nt][ks], acc[1][nt], 0, 0, 0);
        }
      }
    }

    if (tid == 0) {
      unsigned tgt = (unsigned)(t + 1) * WPG_;
      while (__hip_atomic_load(cnt, __ATOMIC_RELAXED, __HIP_MEMORY_SCOPE_AGENT) < tgt) {
        __builtin_amdgcn_s_sleep(1);
      }
    }
    __syncthreads();   // release: h_t visible; h_lds safe to refill

    rp = wp; wp = (wp == 2) ? 0 : wp + 1;
  }

  // final output row: h_{T-1} from global (rp buffer after last rotation)
  if (g == 0)
    out_dot_glb(h_base + (size_t)rp * HU64_, T_ - 1, bg, wout_s, bout, out);
}

// ---------------------------------------------------------------------------
extern "C" void kernel_launch(void* const* d_in, const int* in_sizes, int n_in,
                              void* d_out, int out_size, void* d_ws, size_t ws_size,
                              hipStream_t stream) {
  const int*   tokens = (const int*)d_in[0];
  const float* values = (const float*)d_in[1];
  const float* emb    = (const float*)d_in[2];
  const float* W_ih   = (const float*)d_in[3];
  const float* W_hh   = (const float*)d_in[4];
  const float* b_ih   = (const float*)d_in[5];
  const float* b_hh   = (const float*)d_in[6];
  const float* W_out  = (const float*)d_in[7];
  const float* b_out  = (const float*)d_in[8];
  float* out = (float*)d_out;

  char* ws = (char*)d_ws;
  __hip_bfloat16* x_bf = (__hip_bfloat16*)ws;                         // 16 MB
  u64* h_base = (u64*)(ws + (size_t)T_ * B_ * E_ * 2);                // 3 * 128KB
  unsigned* bars = (unsigned*)(ws + (size_t)T_ * B_ * E_ * 2
                                  + (size_t)3 * HU64_ * sizeof(u64)); // 1 KB

  hipMemsetAsync(h_base, 0, (size_t)3 * HU64_ * sizeof(u64), stream);
  hipMemsetAsync(bars, 0, (size_t)BG_ * 64 * sizeof(unsigned), stream);

  embed_kernel<<<(B_ * T_ * E_) / 256, 256, 0, stream>>>(tokens, values, emb, x_bf);

  // Plain (non-cooperative) launch: 64 blocks on an otherwise-empty 256-CU
  // device are all resident; the hand-rolled per-bg barrier needs no more.
  lstm_kernel<<<dim3(BG_ * WPG_), dim3(256), 0, stream>>>(
      W_ih, W_hh, b_ih, b_hh, W_out, b_out, x_bf, h_base, out, bars);
}

// Round 6
// 2436.286 us; speedup vs baseline: 11.1636x; 1.0453x over previous
//
#include <hip/hip_runtime.h>
#include <hip/hip_bf16.h>

#define B_   128
#define T_   512
#define L_   8
#define E_   128
#define H_   512

// Partition: 4 batch-groups (32 rows each) x 16 WGs = 64 WGs, 256 thr each.
// WG (bg,g): batch rows [bg*32,+32), hidden units [g*32,+32) -> 128 gate rows.
// Wave wv = gate type; per wave N=32 (2 N-tiles), M=32 (2 M-tiles), K=640.
// W fragments in registers (160 VGPRs/wave), h slab staged in LDS per step.
// Plain launch: 64 blocks / 256 CUs all resident; per-bg flag-array barrier.
#define BG_   4
#define WPG_  16
#define JW_   32
#define HU64_ (B_ * H_ / 4)   // u64 per h buffer (16384)
#define GSTR  132             // gbuf row stride (floats): 132&31=4 -> 2-way max

typedef __attribute__((ext_vector_type(8))) short s8v;   // 8 bf16
typedef __attribute__((ext_vector_type(4))) float f4v;   // MFMA acc
typedef unsigned long long u64;

__device__ __forceinline__ float bf16u_to_f(unsigned short s) {
  union { unsigned u; float f; } c; c.u = ((unsigned)s) << 16; return c.f;
}
// LLC-coherent (sc1) accesses: bypass non-coherent per-XCD L2.
__device__ __forceinline__ u64 llc_load8(const void* p) {
  return __hip_atomic_load((const u64*)p, __ATOMIC_RELAXED, __HIP_MEMORY_SCOPE_AGENT);
}
__device__ __forceinline__ void llc_store8(void* p, u64 v) {
  __hip_atomic_store((u64*)p, v, __ATOMIC_RELAXED, __HIP_MEMORY_SCOPE_AGENT);
}
__device__ __forceinline__ unsigned llc_load4(const unsigned* p) {
  return __hip_atomic_load(p, __ATOMIC_RELAXED, __HIP_MEMORY_SCOPE_AGENT);
}
__device__ __forceinline__ void llc_store4(unsigned* p, unsigned v) {
  __hip_atomic_store(p, v, __ATOMIC_RELAXED, __HIP_MEMORY_SCOPE_AGENT);
}
// Fast activations via v_exp_f32 + v_rcp_f32 (~1e-6 abs err; threshold 6.3e-5)
__device__ __forceinline__ float sigf(float x) {
  return __builtin_amdgcn_rcpf(1.f + __expf(-x));
}
__device__ __forceinline__ float tanh_f(float x) {
  return 1.f - 2.f * __builtin_amdgcn_rcpf(1.f + __expf(2.f * x));
}

// All-wave parallel flag poll: lanes 0..15 each load one WG flag (one 64B
// line -> one transaction), wave exits when all >= tgt. No RMW, no release
// sync -- each wave self-releases.
__device__ __forceinline__ void wait_flags(const unsigned* flags, unsigned tgt) {
  const int lane = threadIdx.x & 63;
  const unsigned* p = flags + (lane & 15);
  for (;;) {
    unsigned f = (lane < 16) ? llc_load4(p) : 0xFFFFFFFFu;
    if (__all((int)(f >= tgt))) break;
  }
}

// ---------------------------------------------------------------------------
__global__ void embed_kernel(const int* __restrict__ tokens,
                             const float* __restrict__ values,
                             const float* __restrict__ emb,
                             __hip_bfloat16* __restrict__ x_bf) {
  int idx = blockIdx.x * blockDim.x + threadIdx.x;   // [0, B*T*E)
  int e  = idx & (E_ - 1);
  int bt = idx >> 7;
  int b  = bt >> 9;
  int t  = bt & (T_ - 1);
  const int*   tok = tokens + (size_t)bt * L_;
  const float* val = values + (size_t)bt * L_;
  float acc = 0.f;
#pragma unroll
  for (int l = 0; l < L_; ++l) acc += emb[(size_t)tok[l] * E_ + e] * val[l];
  acc = fmaxf(acc, 0.f);
  x_bf[((size_t)t * B_ + b) * E_ + e] = __float2bfloat16(acc);
}

// ---------------------------------------------------------------------------
// out[b,t] = W_out . h_t + b_out from the LDS-staged (xor-swizzled) slab.
__device__ __forceinline__ void out_dot_lds(const u64* __restrict__ h_lds,
                                            int t, int bg,
                                            const float* __restrict__ wout_s,
                                            float bout, float* __restrict__ out) {
  const int um = threadIdx.x >> 3;
  const int uj = threadIdx.x & 7;
  const u64* row = h_lds + (size_t)um * 128;
  const float* wr = wout_s + uj * 64;
  float p = 0.f;
#pragma unroll
  for (int j = 0; j < 8; ++j) {
    int pc = ((uj * 8 + j) ^ (um & 7)) * 2;
    u64 qa = row[pc], qb = row[pc + 1];
    p += bf16u_to_f((unsigned short)(qa      )) * wr[j * 8 + 0];
    p += bf16u_to_f((unsigned short)(qa >> 16)) * wr[j * 8 + 1];
    p += bf16u_to_f((unsigned short)(qa >> 32)) * wr[j * 8 + 2];
    p += bf16u_to_f((unsigned short)(qa >> 48)) * wr[j * 8 + 3];
    p += bf16u_to_f((unsigned short)(qb      )) * wr[j * 8 + 4];
    p += bf16u_to_f((unsigned short)(qb >> 16)) * wr[j * 8 + 5];
    p += bf16u_to_f((unsigned short)(qb >> 32)) * wr[j * 8 + 6];
    p += bf16u_to_f((unsigned short)(qb >> 48)) * wr[j * 8 + 7];
  }
  p += __shfl_down(p, 4, 8);
  p += __shfl_down(p, 2, 8);
  p += __shfl_down(p, 1, 8);
  if (uj == 0) out[(size_t)(bg * 32 + um) * T_ + t] = p + bout;
}

// Final-step variant: read h_{T-1} from global (LLC).
__device__ __forceinline__ void out_dot_glb(const u64* __restrict__ h,
                                            int t, int bg,
                                            const float* __restrict__ wout_s,
                                            float bout, float* __restrict__ out) {
  const int um = threadIdx.x >> 3;
  const int uj = threadIdx.x & 7;
  const int b  = bg * 32 + um;
  const u64* hr = h + (size_t)b * 128 + uj * 16;
  const float* wr = wout_s + uj * 64;
  float p = 0.f;
#pragma unroll
  for (int kk = 0; kk < 16; ++kk) {
    u64 q = llc_load8(hr + kk);
    p += bf16u_to_f((unsigned short)(q      )) * wr[kk * 4 + 0];
    p += bf16u_to_f((unsigned short)(q >> 16)) * wr[kk * 4 + 1];
    p += bf16u_to_f((unsigned short)(q >> 32)) * wr[kk * 4 + 2];
    p += bf16u_to_f((unsigned short)(q >> 48)) * wr[kk * 4 + 3];
  }
  p += __shfl_down(p, 4, 8);
  p += __shfl_down(p, 2, 8);
  p += __shfl_down(p, 1, 8);
  if (uj == 0) out[(size_t)b * T_ + t] = p + bout;
}

// ---------------------------------------------------------------------------
__global__ void __launch_bounds__(256, 1)
lstm_kernel(const float* __restrict__ W_ih, const float* __restrict__ W_hh,
            const float* __restrict__ b_ih, const float* __restrict__ b_hh,
            const float* __restrict__ W_out, const float* __restrict__ b_out,
            const __hip_bfloat16* __restrict__ x_bf,
            u64* __restrict__ h_base,             // 3 * B*H bf16 (zeroed), u64 view
            float* __restrict__ out,              // B*T f32
            unsigned* __restrict__ bars) {        // BG_ x 16 flags, 256B apart
  __shared__ __align__(16) u64   h_lds[32 * 128];  // 32 rows x 64 16B chunks, xor-swizzled
  __shared__ __align__(16) float gbuf[32][GSTR];   // gates staging
  __shared__ __align__(16) float bias_s[128];
  __shared__ float wout_s[H_];

  const int tid = threadIdx.x;
  const int wg  = blockIdx.x;
  const int bg  = wg >> 4;            // 0..3
  const int g   = wg & (WPG_ - 1);    // 0..15
  const int j0g = g * JW_;

  const int wv   = tid >> 6;          // wave = gate type 0..3
  const int lane = tid & 63;
  const int m16  = lane & 15;
  const int q    = lane >> 4;
  const int sw   = m16 & 7;           // xor-swizzle key

  // ---- one-time: W fragments -> registers (B operand, 2 N-tiles x 20 K) --
  s8v bfrag[2][20];
#pragma unroll
  for (int nt = 0; nt < 2; ++nt) {
    const int r = wv * H_ + j0g + nt * 16 + m16;        // global gate row
    const float* wih_r = W_ih + (size_t)r * E_;
    const float* whh_r = W_hh + (size_t)r * H_;
#pragma unroll
    for (int ks = 0; ks < 20; ++ks) {
      s8v v;
#pragma unroll
      for (int i = 0; i < 8; ++i) {
        int k = ks * 32 + q * 8 + i;
        float w = (k < E_) ? wih_r[k] : whh_r[k - E_];
        __hip_bfloat16 hb = __float2bfloat16(w);
        v[i] = *(short*)&hb;
      }
      bfrag[nt][ks] = v;
    }
  }
  if (tid < 128) {
    int gt = tid >> 5, jl = tid & 31;
    int r = gt * H_ + j0g + jl;
    bias_s[tid] = b_ih[r] + b_hh[r];
  }
  if (g == 0) for (int i = tid; i < H_; i += 256) wout_s[i] = W_out[i];

  // ---- per-step identities ----------------------------------------------
  const int um = tid >> 3;            // update/out/fill row
  const int jb = (tid & 7) * 4;       // update: 4 hidden units
  const int ub = bg * 32 + um;
  const int fc = tid & 7;             // fill: chunk base
  float cst[4] = {0.f, 0.f, 0.f, 0.f};
  const float bout = b_out[0];
  unsigned* flags  = bars + bg * 64;  // 16 u32 flags in one 64B line
  unsigned* myflag = flags + g;

  int rp = 2, wp = 0;                 // h_{-1}=zeros in buf2; h_t -> buf[t%3]
  f4v acc[2][2];

  // prologue: x-part of step 0
  {
    const __hip_bfloat16* ax0 = x_bf + (size_t)(bg * 32 + m16) * E_ + q * 8;
    const __hip_bfloat16* ax1 = x_bf + (size_t)(bg * 32 + 16 + m16) * E_ + q * 8;
    f4v z = {0.f, 0.f, 0.f, 0.f};
    acc[0][0] = z; acc[0][1] = z; acc[1][0] = z; acc[1][1] = z;
#pragma unroll
    for (int ks = 0; ks < 4; ++ks) {
      s8v a0 = *(const s8v*)(ax0 + ks * 32);
      s8v a1 = *(const s8v*)(ax1 + ks * 32);
#pragma unroll
      for (int nt = 0; nt < 2; ++nt) {
        acc[0][nt] = __builtin_amdgcn_mfma_f32_16x16x32_bf16(a0, bfrag[nt][ks], acc[0][nt], 0, 0, 0);
        acc[1][nt] = __builtin_amdgcn_mfma_f32_16x16x32_bf16(a1, bfrag[nt][ks], acc[1][nt], 0, 0, 0);
      }
    }
  }
  __syncthreads();   // bias/wout ready

  for (int t = 0; t < T_; ++t) {
    const u64* h_prev = h_base + (size_t)rp * HU64_;
    u64*       h_next = h_base + (size_t)wp * HU64_;

    // ---- wait for h_{t-1} (t=0: flags start at 0, trivially passes) -----
    wait_flags(flags, (unsigned)t);

    // ---- cooperative fill: h_{t-1} slab -> LDS (xor-swizzled chunks) ----
    {
      const u64* src = h_prev + (size_t)(bg * 32 + um) * 128;
      u64 v[16];
#pragma unroll
      for (int j = 0; j < 8; ++j) {
        int lc = fc + 8 * j;
        v[2 * j]     = llc_load8(src + lc * 2);
        v[2 * j + 1] = llc_load8(src + lc * 2 + 1);
      }
      u64* dst = h_lds + (size_t)um * 128;
#pragma unroll
      for (int j = 0; j < 8; ++j) {
        int pc = ((fc + 8 * j) ^ (um & 7)) * 2;
        dst[pc]     = v[2 * j];
        dst[pc + 1] = v[2 * j + 1];
      }
    }
    __syncthreads();   // fill complete

    // ---- h-part MFMAs (K=512 from LDS; B from registers) ----------------
    {
      const u64* al0 = h_lds + (size_t)m16 * 128;
      const u64* al1 = h_lds + (size_t)(16 + m16) * 128;
#pragma unroll
      for (int ks4 = 0; ks4 < 16; ++ks4) {
        int pc = ((ks4 * 4 + q) ^ sw) * 2;
        s8v a0 = *(const s8v*)(al0 + pc);
        s8v a1 = *(const s8v*)(al1 + pc);
#pragma unroll
        for (int nt = 0; nt < 2; ++nt) {
          acc[0][nt] = __builtin_amdgcn_mfma_f32_16x16x32_bf16(a0, bfrag[nt][4 + ks4], acc[0][nt], 0, 0, 0);
          acc[1][nt] = __builtin_amdgcn_mfma_f32_16x16x32_bf16(a1, bfrag[nt][4 + ks4], acc[1][nt], 0, 0, 0);
        }
      }
    }

    // ---- stage gates to LDS (D: row=quad*4+r, col=m16) ------------------
#pragma unroll
    for (int mt = 0; mt < 2; ++mt)
#pragma unroll
      for (int nt = 0; nt < 2; ++nt)
#pragma unroll
        for (int r = 0; r < 4; ++r)
          gbuf[mt * 16 + q * 4 + r][wv * 32 + nt * 16 + m16] = acc[mt][nt][r];
    __syncthreads();   // gates ready

    // ---- x-part of step t+1 (overlaps pointwise latency) ----------------
    if (t + 1 < T_) {
      const __hip_bfloat16* xt = x_bf + (size_t)(t + 1) * B_ * E_;
      const __hip_bfloat16* ax0 = xt + (size_t)(bg * 32 + m16) * E_ + q * 8;
      const __hip_bfloat16* ax1 = xt + (size_t)(bg * 32 + 16 + m16) * E_ + q * 8;
      f4v z = {0.f, 0.f, 0.f, 0.f};
      acc[0][0] = z; acc[0][1] = z; acc[1][0] = z; acc[1][1] = z;
#pragma unroll
      for (int ks = 0; ks < 4; ++ks) {
        s8v a0 = *(const s8v*)(ax0 + ks * 32);
        s8v a1 = *(const s8v*)(ax1 + ks * 32);
#pragma unroll
        for (int nt = 0; nt < 2; ++nt) {
          acc[0][nt] = __builtin_amdgcn_mfma_f32_16x16x32_bf16(a0, bfrag[nt][ks], acc[0][nt], 0, 0, 0);
          acc[1][nt] = __builtin_amdgcn_mfma_f32_16x16x32_bf16(a1, bfrag[nt][ks], acc[1][nt], 0, 0, 0);
        }
      }
    }

    // ---- pointwise update: 4 hidden units per thread (vector LDS reads) -
    {
      const float* gr = &gbuf[0][0] + (size_t)um * GSTR;
      f4v vi = *(const f4v*)(gr + jb);
      f4v vf = *(const f4v*)(gr + 32 + jb);
      f4v vg = *(const f4v*)(gr + 64 + jb);
      f4v vo = *(const f4v*)(gr + 96 + jb);
      f4v bi = *(const f4v*)(bias_s + jb);
      f4v bf = *(const f4v*)(bias_s + 32 + jb);
      f4v bgc = *(const f4v*)(bias_s + 64 + jb);
      f4v bo = *(const f4v*)(bias_s + 96 + jb);
      u64 packed = 0;
#pragma unroll
      for (int qq = 0; qq < 4; ++qq) {
        float si = sigf(vi[qq] + bi[qq]);
        float sf = sigf(vf[qq] + bf[qq]);
        float tg = tanh_f(vg[qq] + bgc[qq]);
        float so = sigf(vo[qq] + bo[qq]);
        cst[qq] = sf * cst[qq] + si * tg;
        float h = so * tanh_f(cst[qq]);
        __hip_bfloat16 hb = __float2bfloat16(h);
        packed |= (u64)(*(unsigned short*)&hb) << (16 * qq);
      }
      llc_store8(h_next + (size_t)ub * 128 + ((j0g + jb) >> 2), packed);
    }

    // ---- off-critical-path work while h stores drain --------------------
    if (g == 0 && t > 0)               // h_{t-1} still staged in LDS
      out_dot_lds(h_lds, t - 1, bg, wout_s, bout, out);

    __syncthreads();   // all 256 threads' sc1 h stores acked at LLC
    if (tid == 0) llc_store4(myflag, (unsigned)(t + 1));

    rp = wp; wp = (wp == 2) ? 0 : wp + 1;
  }

  // final output row: h_{T-1} from global (rp buffer after last rotation)
  wait_flags(flags, (unsigned)T_);
  if (g == 0)
    out_dot_glb(h_base + (size_t)rp * HU64_, T_ - 1, bg, wout_s, bout, out);
}

// ---------------------------------------------------------------------------
extern "C" void kernel_launch(void* const* d_in, const int* in_sizes, int n_in,
                              void* d_out, int out_size, void* d_ws, size_t ws_size,
                              hipStream_t stream) {
  const int*   tokens = (const int*)d_in[0];
  const float* values = (const float*)d_in[1];
  const float* emb    = (const float*)d_in[2];
  const float* W_ih   = (const float*)d_in[3];
  const float* W_hh   = (const float*)d_in[4];
  const float* b_ih   = (const float*)d_in[5];
  const float* b_hh   = (const float*)d_in[6];
  const float* W_out  = (const float*)d_in[7];
  const float* b_out  = (const float*)d_in[8];
  float* out = (float*)d_out;

  char* ws = (char*)d_ws;
  __hip_bfloat16* x_bf = (__hip_bfloat16*)ws;                         // 16 MB
  u64* h_base = (u64*)(ws + (size_t)T_ * B_ * E_ * 2);                // 3 * 128KB
  unsigned* bars = (unsigned*)(ws + (size_t)T_ * B_ * E_ * 2
                                  + (size_t)3 * HU64_ * sizeof(u64)); // 1 KB

  hipMemsetAsync(h_base, 0, (size_t)3 * HU64_ * sizeof(u64), stream);
  hipMemsetAsync(bars, 0, (size_t)BG_ * 64 * sizeof(unsigned), stream);

  embed_kernel<<<(B_ * T_ * E_) / 256, 256, 0, stream>>>(tokens, values, emb, x_bf);

  lstm_kernel<<<dim3(BG_ * WPG_), dim3(256), 0, stream>>>(
      W_ih, W_hh, b_ih, b_hh, W_out, b_out, x_bf, h_base, out, bars);
}

// Round 7
// 2336.695 us; speedup vs baseline: 11.6394x; 1.0426x over previous
//
#include <hip/hip_runtime.h>
#include <hip/hip_bf16.h>

#define B_   128
#define T_   512
#define L_   8
#define E_   128
#define H_   512

// Partition: 4 batch-groups (32 rows each) x 16 WGs = 64 WGs, 256 thr each.
// WG (bg,g): batch rows [bg*32,+32), hidden units [g*32,+32) -> 128 gate rows.
// Wave wv = gate type; per wave N=32 (2 N-tiles), M=32 (2 M-tiles), K=640.
// W fragments in registers, h slab staged in LDS per step.
// Sync protocol: per-WAVE flags (64 per bg). Producer chain is minimal:
// pointwise -> h sc1-store -> per-wave vmcnt(0) -> flag. out_dot and the
// x-part of step t+1 execute in the poll shadow.
#define BG_   4
#define WPG_  16
#define JW_   32
#define HU64_ (B_ * H_ / 4)   // u64 per h buffer (16384)
#define GSTR  132             // gbuf row stride (floats)

typedef __attribute__((ext_vector_type(8))) short s8v;   // 8 bf16
typedef __attribute__((ext_vector_type(4))) float f4v;   // MFMA acc
typedef unsigned long long u64;

__device__ __forceinline__ float bf16u_to_f(unsigned short s) {
  union { unsigned u; float f; } c; c.u = ((unsigned)s) << 16; return c.f;
}
// LLC-coherent (sc1) accesses: bypass non-coherent per-XCD L2.
__device__ __forceinline__ u64 llc_load8(const void* p) {
  return __hip_atomic_load((const u64*)p, __ATOMIC_RELAXED, __HIP_MEMORY_SCOPE_AGENT);
}
__device__ __forceinline__ void llc_store8(void* p, u64 v) {
  __hip_atomic_store((u64*)p, v, __ATOMIC_RELAXED, __HIP_MEMORY_SCOPE_AGENT);
}
__device__ __forceinline__ unsigned llc_load4(const unsigned* p) {
  return __hip_atomic_load(p, __ATOMIC_RELAXED, __HIP_MEMORY_SCOPE_AGENT);
}
__device__ __forceinline__ void llc_store4(unsigned* p, unsigned v) {
  __hip_atomic_store(p, v, __ATOMIC_RELAXED, __HIP_MEMORY_SCOPE_AGENT);
}
// Fast activations via v_exp_f32 + v_rcp_f32 (~1e-6 abs err)
__device__ __forceinline__ float sigf(float x) {
  return __builtin_amdgcn_rcpf(1.f + __expf(-x));
}
__device__ __forceinline__ float tanh_f(float x) {
  return 1.f - 2.f * __builtin_amdgcn_rcpf(1.f + __expf(2.f * x));
}

// All-wave poll of 64 per-wave flags: lane i polls flags[i] (256B = 4
// transactions / iteration). Wave self-releases when all >= tgt.
__device__ __forceinline__ void wait_flags64(const unsigned* flags, unsigned tgt) {
  const unsigned* p = flags + (threadIdx.x & 63);
  while (!__all((int)(llc_load4(p) >= tgt))) { }
}

// ---------------------------------------------------------------------------
__global__ void embed_kernel(const int* __restrict__ tokens,
                             const float* __restrict__ values,
                             const float* __restrict__ emb,
                             __hip_bfloat16* __restrict__ x_bf) {
  int idx = blockIdx.x * blockDim.x + threadIdx.x;   // [0, B*T*E)
  int e  = idx & (E_ - 1);
  int bt = idx >> 7;
  int b  = bt >> 9;
  int t  = bt & (T_ - 1);
  const int*   tok = tokens + (size_t)bt * L_;
  const float* val = values + (size_t)bt * L_;
  float acc = 0.f;
#pragma unroll
  for (int l = 0; l < L_; ++l) acc += emb[(size_t)tok[l] * E_ + e] * val[l];
  acc = fmaxf(acc, 0.f);
  x_bf[((size_t)t * B_ + b) * E_ + e] = __float2bfloat16(acc);
}

// ---------------------------------------------------------------------------
// out[b,t] = W_out . h_t + b_out from the LDS-staged (xor-swizzled) slab.
__device__ __forceinline__ void out_dot_lds(const u64* __restrict__ h_lds,
                                            int t, int bg,
                                            const float* __restrict__ wout_s,
                                            float bout, float* __restrict__ out) {
  const int um = threadIdx.x >> 3;
  const int uj = threadIdx.x & 7;
  const u64* row = h_lds + (size_t)um * 128;
  const float* wr = wout_s + uj * 64;
  float p = 0.f;
#pragma unroll
  for (int j = 0; j < 8; ++j) {
    int pc = ((uj * 8 + j) ^ (um & 7)) * 2;
    u64 qa = row[pc], qb = row[pc + 1];
    p += bf16u_to_f((unsigned short)(qa      )) * wr[j * 8 + 0];
    p += bf16u_to_f((unsigned short)(qa >> 16)) * wr[j * 8 + 1];
    p += bf16u_to_f((unsigned short)(qa >> 32)) * wr[j * 8 + 2];
    p += bf16u_to_f((unsigned short)(qa >> 48)) * wr[j * 8 + 3];
    p += bf16u_to_f((unsigned short)(qb      )) * wr[j * 8 + 4];
    p += bf16u_to_f((unsigned short)(qb >> 16)) * wr[j * 8 + 5];
    p += bf16u_to_f((unsigned short)(qb >> 32)) * wr[j * 8 + 6];
    p += bf16u_to_f((unsigned short)(qb >> 48)) * wr[j * 8 + 7];
  }
  p += __shfl_down(p, 4, 8);
  p += __shfl_down(p, 2, 8);
  p += __shfl_down(p, 1, 8);
  if (uj == 0) out[(size_t)(bg * 32 + um) * T_ + t] = p + bout;
}

// Final-step variant: read h_{T-1} from global (LLC).
__device__ __forceinline__ void out_dot_glb(const u64* __restrict__ h,
                                            int t, int bg,
                                            const float* __restrict__ wout_s,
                                            float bout, float* __restrict__ out) {
  const int um = threadIdx.x >> 3;
  const int uj = threadIdx.x & 7;
  const int b  = bg * 32 + um;
  const u64* hr = h + (size_t)b * 128 + uj * 16;
  const float* wr = wout_s + uj * 64;
  float p = 0.f;
#pragma unroll
  for (int kk = 0; kk < 16; ++kk) {
    u64 q = llc_load8(hr + kk);
    p += bf16u_to_f((unsigned short)(q      )) * wr[kk * 4 + 0];
    p += bf16u_to_f((unsigned short)(q >> 16)) * wr[kk * 4 + 1];
    p += bf16u_to_f((unsigned short)(q >> 32)) * wr[kk * 4 + 2];
    p += bf16u_to_f((unsigned short)(q >> 48)) * wr[kk * 4 + 3];
  }
  p += __shfl_down(p, 4, 8);
  p += __shfl_down(p, 2, 8);
  p += __shfl_down(p, 1, 8);
  if (uj == 0) out[(size_t)b * T_ + t] = p + bout;
}

// ---------------------------------------------------------------------------
__global__ void __launch_bounds__(256, 1)
lstm_kernel(const float* __restrict__ W_ih, const float* __restrict__ W_hh,
            const float* __restrict__ b_ih, const float* __restrict__ b_hh,
            const float* __restrict__ W_out, const float* __restrict__ b_out,
            const __hip_bfloat16* __restrict__ x_bf,
            u64* __restrict__ h_base,             // 3 * B*H bf16 (zeroed), u64 view
            float* __restrict__ out,              // B*T f32
            unsigned* __restrict__ bars) {        // BG_ x 64 per-wave flags
  __shared__ __align__(16) u64   h_lds[32 * 128];  // 32 rows x 64 16B chunks, xor-swizzled
  __shared__ __align__(16) float gbuf[32][GSTR];   // gates staging
  __shared__ __align__(16) float bias_s[128];
  __shared__ float wout_s[H_];

  const int tid = threadIdx.x;
  const int wg  = blockIdx.x;
  const int bg  = wg >> 4;            // 0..3
  const int g   = wg & (WPG_ - 1);    // 0..15
  const int j0g = g * JW_;

  const int wv   = tid >> 6;          // wave = gate type 0..3
  const int lane = tid & 63;
  const int m16  = lane & 15;
  const int q    = lane >> 4;
  const int sw   = m16 & 7;           // xor-swizzle key

  // ---- one-time: W fragments -> registers (B operand, 2 N-tiles x 20 K) --
  s8v bfrag[2][20];
#pragma unroll
  for (int nt = 0; nt < 2; ++nt) {
    const int r = wv * H_ + j0g + nt * 16 + m16;        // global gate row
    const float* wih_r = W_ih + (size_t)r * E_;
    const float* whh_r = W_hh + (size_t)r * H_;
#pragma unroll
    for (int ks = 0; ks < 20; ++ks) {
      s8v v;
#pragma unroll
      for (int i = 0; i < 8; ++i) {
        int k = ks * 32 + q * 8 + i;
        float w = (k < E_) ? wih_r[k] : whh_r[k - E_];
        __hip_bfloat16 hb = __float2bfloat16(w);
        v[i] = *(short*)&hb;
      }
      bfrag[nt][ks] = v;
    }
  }
  if (tid < 128) {
    int gt = tid >> 5, jl = tid & 31;
    int r = gt * H_ + j0g + jl;
    bias_s[tid] = b_ih[r] + b_hh[r];
  }
  if (g == 0) for (int i = tid; i < H_; i += 256) wout_s[i] = W_out[i];

  // ---- per-step identities ----------------------------------------------
  const int um = tid >> 3;            // update/out/fill row
  const int jb = (tid & 7) * 4;       // update: 4 hidden units
  const int ub = bg * 32 + um;
  const int fc = tid & 7;             // fill: chunk base
  float cst[4] = {0.f, 0.f, 0.f, 0.f};
  const float bout = b_out[0];
  unsigned* flags  = bars + bg * 64;  // 64 per-wave flags (256B)
  unsigned* myflag = flags + (g << 2) + wv;

  int rp = 2, wp = 0;                 // h_{-1}=zeros in buf2; h_t -> buf[t%3]
  f4v acc[2][2];

  // prologue: x-part of step 0
  {
    const __hip_bfloat16* ax0 = x_bf + (size_t)(bg * 32 + m16) * E_ + q * 8;
    const __hip_bfloat16* ax1 = x_bf + (size_t)(bg * 32 + 16 + m16) * E_ + q * 8;
    f4v z = {0.f, 0.f, 0.f, 0.f};
    acc[0][0] = z; acc[0][1] = z; acc[1][0] = z; acc[1][1] = z;
#pragma unroll
    for (int ks = 0; ks < 4; ++ks) {
      s8v a0 = *(const s8v*)(ax0 + ks * 32);
      s8v a1 = *(const s8v*)(ax1 + ks * 32);
#pragma unroll
      for (int nt = 0; nt < 2; ++nt) {
        acc[0][nt] = __builtin_amdgcn_mfma_f32_16x16x32_bf16(a0, bfrag[nt][ks], acc[0][nt], 0, 0, 0);
        acc[1][nt] = __builtin_amdgcn_mfma_f32_16x16x32_bf16(a1, bfrag[nt][ks], acc[1][nt], 0, 0, 0);
      }
    }
  }
  __syncthreads();   // bias/wout ready

  for (int t = 0; t < T_; ++t) {
    const u64* h_prev = h_base + (size_t)rp * HU64_;
    u64*       h_next = h_base + (size_t)wp * HU64_;

    // ---- wait for all 64 producer waves of step t-1 ---------------------
    wait_flags64(flags, (unsigned)t);

    // ---- cooperative fill: h_{t-1} slab -> LDS (xor-swizzled chunks) ----
    {
      const u64* src = h_prev + (size_t)(bg * 32 + um) * 128;
      u64 v[16];
#pragma unroll
      for (int j = 0; j < 8; ++j) {
        int lc = fc + 8 * j;
        v[2 * j]     = llc_load8(src + lc * 2);
        v[2 * j + 1] = llc_load8(src + lc * 2 + 1);
      }
      u64* dst = h_lds + (size_t)um * 128;
#pragma unroll
      for (int j = 0; j < 8; ++j) {
        int pc = ((fc + 8 * j) ^ (um & 7)) * 2;
        dst[pc]     = v[2 * j];
        dst[pc + 1] = v[2 * j + 1];
      }
    }
    __syncthreads();   // fill complete

    // ---- h-part MFMAs (K=512 from LDS; B from registers) ----------------
    {
      const u64* al0 = h_lds + (size_t)m16 * 128;
      const u64* al1 = h_lds + (size_t)(16 + m16) * 128;
#pragma unroll
      for (int ks4 = 0; ks4 < 16; ++ks4) {
        int pc = ((ks4 * 4 + q) ^ sw) * 2;
        s8v a0 = *(const s8v*)(al0 + pc);
        s8v a1 = *(const s8v*)(al1 + pc);
#pragma unroll
        for (int nt = 0; nt < 2; ++nt) {
          acc[0][nt] = __builtin_amdgcn_mfma_f32_16x16x32_bf16(a0, bfrag[nt][4 + ks4], acc[0][nt], 0, 0, 0);
          acc[1][nt] = __builtin_amdgcn_mfma_f32_16x16x32_bf16(a1, bfrag[nt][4 + ks4], acc[1][nt], 0, 0, 0);
        }
      }
    }

    // ---- stage gates to LDS (D: row=quad*4+r, col=m16) ------------------
#pragma unroll
    for (int mt = 0; mt < 2; ++mt)
#pragma unroll
      for (int nt = 0; nt < 2; ++nt)
#pragma unroll
        for (int r = 0; r < 4; ++r)
          gbuf[mt * 16 + q * 4 + r][wv * 32 + nt * 16 + m16] = acc[mt][nt][r];
    __syncthreads();   // gates ready

    // ---- CRITICAL PATH: pointwise -> h store -> drain -> flag -----------
    {
      const float* gr = &gbuf[0][0] + (size_t)um * GSTR;
      f4v vi = *(const f4v*)(gr + jb);
      f4v vf = *(const f4v*)(gr + 32 + jb);
      f4v vg = *(const f4v*)(gr + 64 + jb);
      f4v vo = *(const f4v*)(gr + 96 + jb);
      f4v bi = *(const f4v*)(bias_s + jb);
      f4v bf = *(const f4v*)(bias_s + 32 + jb);
      f4v bgc = *(const f4v*)(bias_s + 64 + jb);
      f4v bo = *(const f4v*)(bias_s + 96 + jb);
      u64 packed = 0;
#pragma unroll
      for (int qq = 0; qq < 4; ++qq) {
        float si = sigf(vi[qq] + bi[qq]);
        float sf = sigf(vf[qq] + bf[qq]);
        float tg = tanh_f(vg[qq] + bgc[qq]);
        float so = sigf(vo[qq] + bo[qq]);
        cst[qq] = sf * cst[qq] + si * tg;
        float h = so * tanh_f(cst[qq]);
        __hip_bfloat16 hb = __float2bfloat16(h);
        packed |= (u64)(*(unsigned short*)&hb) << (16 * qq);
      }
      llc_store8(h_next + (size_t)ub * 128 + ((j0g + jb) >> 2), packed);
    }
    // per-wave: drain own sc1 stores (acked at LLC), then publish wave flag
    asm volatile("s_waitcnt vmcnt(0)" ::: "memory");
    if (lane == 0) llc_store4(myflag, (unsigned)(t + 1));

    // ---- poll-shadow work (other WGs are polling/filling) ---------------
    if (g == 0 && t > 0)               // h_{t-1} still staged in LDS
      out_dot_lds(h_lds, t - 1, bg, wout_s, bout, out);

    if (t + 1 < T_) {                  // x-part of step t+1
      const __hip_bfloat16* xt = x_bf + (size_t)(t + 1) * B_ * E_;
      const __hip_bfloat16* ax0 = xt + (size_t)(bg * 32 + m16) * E_ + q * 8;
      const __hip_bfloat16* ax1 = xt + (size_t)(bg * 32 + 16 + m16) * E_ + q * 8;
      f4v z = {0.f, 0.f, 0.f, 0.f};
      acc[0][0] = z; acc[0][1] = z; acc[1][0] = z; acc[1][1] = z;
#pragma unroll
      for (int ks = 0; ks < 4; ++ks) {
        s8v a0 = *(const s8v*)(ax0 + ks * 32);
        s8v a1 = *(const s8v*)(ax1 + ks * 32);
#pragma unroll
        for (int nt = 0; nt < 2; ++nt) {
          acc[0][nt] = __builtin_amdgcn_mfma_f32_16x16x32_bf16(a0, bfrag[nt][ks], acc[0][nt], 0, 0, 0);
          acc[1][nt] = __builtin_amdgcn_mfma_f32_16x16x32_bf16(a1, bfrag[nt][ks], acc[1][nt], 0, 0, 0);
        }
      }
    }

    __syncthreads();   // protect h_lds: all reads done before next fill

    rp = wp; wp = (wp == 2) ? 0 : wp + 1;
  }

  // final output row: h_{T-1} from global (rp buffer after last rotation)
  wait_flags64(flags, (unsigned)T_);
  if (g == 0)
    out_dot_glb(h_base + (size_t)rp * HU64_, T_ - 1, bg, wout_s, bout, out);
}

// ---------------------------------------------------------------------------
extern "C" void kernel_launch(void* const* d_in, const int* in_sizes, int n_in,
                              void* d_out, int out_size, void* d_ws, size_t ws_size,
                              hipStream_t stream) {
  const int*   tokens = (const int*)d_in[0];
  const float* values = (const float*)d_in[1];
  const float* emb    = (const float*)d_in[2];
  const float* W_ih   = (const float*)d_in[3];
  const float* W_hh   = (const float*)d_in[4];
  const float* b_ih   = (const float*)d_in[5];
  const float* b_hh   = (const float*)d_in[6];
  const float* W_out  = (const float*)d_in[7];
  const float* b_out  = (const float*)d_in[8];
  float* out = (float*)d_out;

  char* ws = (char*)d_ws;
  __hip_bfloat16* x_bf = (__hip_bfloat16*)ws;                         // 16 MB
  u64* h_base = (u64*)(ws + (size_t)T_ * B_ * E_ * 2);                // 3 * 128KB
  unsigned* bars = (unsigned*)(ws + (size_t)T_ * B_ * E_ * 2
                                  + (size_t)3 * HU64_ * sizeof(u64)); // 1 KB

  hipMemsetAsync(h_base, 0, (size_t)3 * HU64_ * sizeof(u64), stream);
  hipMemsetAsync(bars, 0, (size_t)BG_ * 64 * sizeof(unsigned), stream);

  embed_kernel<<<(B_ * T_ * E_) / 256, 256, 0, stream>>>(tokens, values, emb, x_bf);

  lstm_kernel<<<dim3(BG_ * WPG_), dim3(256), 0, stream>>>(
      W_ih, W_hh, b_ih, b_hh, W_out, b_out, x_bf, h_base, out, bars);
}

// Round 10
// 2296.831 us; speedup vs baseline: 11.8414x; 1.0174x over previous
//
#include <hip/hip_runtime.h>
#include <hip/hip_bf16.h>

#define B_   128
#define T_   512
#define L_   8
#define E_   128
#define H_   512

// Partition: 4 batch-groups (32 rows each) x 16 WGs = 64 WGs, 256 thr each.
// WG (bg,g): batch rows [bg*32,+32), hidden units [g*32,+32) -> 128 gate rows.
// Wave wv = gate type; per wave N=32 (2 N-tiles), M=32 (2 M-tiles), K=640.
// W fragments in registers, h slab staged in LDS per step.
// Sync: per-wave flags (64/bg). Producer chain: pointwise -> h sc1-store ->
// per-wave vmcnt(0) -> flag. ONLY wave 0 of each WG polls (s_sleep backoff);
// waves 1-3 released by the loop-head __syncthreads (which doubles as the
// h_lds-protect barrier). out_dot + x-part(t+1) run in the poll shadow.
#define BG_   4
#define WPG_  16
#define JW_   32
#define HU64_ (B_ * H_ / 4)   // u64 per h buffer (16384)
#define GSTR  132             // gbuf row stride (floats)

typedef __attribute__((ext_vector_type(8))) short s8v;   // 8 bf16
typedef __attribute__((ext_vector_type(4))) float f4v;   // MFMA acc
typedef unsigned long long u64;

__device__ __forceinline__ float bf16u_to_f(unsigned short s) {
  union { unsigned u; float f; } c; c.u = ((unsigned)s) << 16; return c.f;
}
// LLC-coherent (sc1) accesses: bypass non-coherent per-XCD L2.
__device__ __forceinline__ u64 llc_load8(const void* p) {
  return __hip_atomic_load((const u64*)p, __ATOMIC_RELAXED, __HIP_MEMORY_SCOPE_AGENT);
}
__device__ __forceinline__ void llc_store8(void* p, u64 v) {
  __hip_atomic_store((u64*)p, v, __ATOMIC_RELAXED, __HIP_MEMORY_SCOPE_AGENT);
}
__device__ __forceinline__ unsigned llc_load4(const unsigned* p) {
  return __hip_atomic_load(p, __ATOMIC_RELAXED, __HIP_MEMORY_SCOPE_AGENT);
}
__device__ __forceinline__ void llc_store4(unsigned* p, unsigned v) {
  __hip_atomic_store(p, v, __ATOMIC_RELAXED, __HIP_MEMORY_SCOPE_AGENT);
}
// Fast activations via v_exp_f32 + v_rcp_f32 (~1e-6 abs err)
__device__ __forceinline__ float sigf(float x) {
  return __builtin_amdgcn_rcpf(1.f + __expf(-x));
}
__device__ __forceinline__ float tanh_f(float x) {
  return 1.f - 2.f * __builtin_amdgcn_rcpf(1.f + __expf(2.f * x));
}

// Wave-0-only poll of 64 per-wave flags: lane i polls flags[i]; s_sleep(1)
// backoff keeps LLC bank pressure low (poll storm was R7's hidden cost).
__device__ __forceinline__ void wait_flags64(const unsigned* flags, unsigned tgt) {
  const unsigned* p = flags + (threadIdx.x & 63);
  while (!__all((int)(llc_load4(p) >= tgt))) {
    __builtin_amdgcn_s_sleep(1);
  }
}

// ---------------------------------------------------------------------------
__global__ void embed_kernel(const int* __restrict__ tokens,
                             const float* __restrict__ values,
                             const float* __restrict__ emb,
                             __hip_bfloat16* __restrict__ x_bf) {
  int idx = blockIdx.x * blockDim.x + threadIdx.x;   // [0, B*T*E)
  int e  = idx & (E_ - 1);
  int bt = idx >> 7;
  int b  = bt >> 9;
  int t  = bt & (T_ - 1);
  const int*   tok = tokens + (size_t)bt * L_;
  const float* val = values + (size_t)bt * L_;
  float acc = 0.f;
#pragma unroll
  for (int l = 0; l < L_; ++l) acc += emb[(size_t)tok[l] * E_ + e] * val[l];
  acc = fmaxf(acc, 0.f);
  x_bf[((size_t)t * B_ + b) * E_ + e] = __float2bfloat16(acc);
}

// ---------------------------------------------------------------------------
// out[b,t] = W_out . h_t + b_out from the LDS-staged (xor-swizzled) slab.
__device__ __forceinline__ void out_dot_lds(const u64* __restrict__ h_lds,
                                            int t, int bg,
                                            const float* __restrict__ wout_s,
                                            float bout, float* __restrict__ out) {
  const int um = threadIdx.x >> 3;
  const int uj = threadIdx.x & 7;
  const u64* row = h_lds + (size_t)um * 128;
  const float* wr = wout_s + uj * 64;
  float p = 0.f;
#pragma unroll
  for (int j = 0; j < 8; ++j) {
    int pc = ((uj * 8 + j) ^ (um & 7)) * 2;
    u64 qa = row[pc], qb = row[pc + 1];
    p += bf16u_to_f((unsigned short)(qa      )) * wr[j * 8 + 0];
    p += bf16u_to_f((unsigned short)(qa >> 16)) * wr[j * 8 + 1];
    p += bf16u_to_f((unsigned short)(qa >> 32)) * wr[j * 8 + 2];
    p += bf16u_to_f((unsigned short)(qa >> 48)) * wr[j * 8 + 3];
    p += bf16u_to_f((unsigned short)(qb      )) * wr[j * 8 + 4];
    p += bf16u_to_f((unsigned short)(qb >> 16)) * wr[j * 8 + 5];
    p += bf16u_to_f((unsigned short)(qb >> 32)) * wr[j * 8 + 6];
    p += bf16u_to_f((unsigned short)(qb >> 48)) * wr[j * 8 + 7];
  }
  p += __shfl_down(p, 4, 8);
  p += __shfl_down(p, 2, 8);
  p += __shfl_down(p, 1, 8);
  if (uj == 0) out[(size_t)(bg * 32 + um) * T_ + t] = p + bout;
}

// Final-step variant: read h_{T-1} from global (LLC).
__device__ __forceinline__ void out_dot_glb(const u64* __restrict__ h,
                                            int t, int bg,
                                            const float* __restrict__ wout_s,
                                            float bout, float* __restrict__ out) {
  const int um = threadIdx.x >> 3;
  const int uj = threadIdx.x & 7;
  const int b  = bg * 32 + um;
  const u64* hr = h + (size_t)b * 128 + uj * 16;
  const float* wr = wout_s + uj * 64;
  float p = 0.f;
#pragma unroll
  for (int kk = 0; kk < 16; ++kk) {
    u64 q = llc_load8(hr + kk);
    p += bf16u_to_f((unsigned short)(q      )) * wr[kk * 4 + 0];
    p += bf16u_to_f((unsigned short)(q >> 16)) * wr[kk * 4 + 1];
    p += bf16u_to_f((unsigned short)(q >> 32)) * wr[kk * 4 + 2];
    p += bf16u_to_f((unsigned short)(q >> 48)) * wr[kk * 4 + 3];
  }
  p += __shfl_down(p, 4, 8);
  p += __shfl_down(p, 2, 8);
  p += __shfl_down(p, 1, 8);
  if (uj == 0) out[(size_t)b * T_ + t] = p + bout;
}

// ---------------------------------------------------------------------------
__global__ void __launch_bounds__(256, 1)
lstm_kernel(const float* __restrict__ W_ih, const float* __restrict__ W_hh,
            const float* __restrict__ b_ih, const float* __restrict__ b_hh,
            const float* __restrict__ W_out, const float* __restrict__ b_out,
            const __hip_bfloat16* __restrict__ x_bf,
            u64* __restrict__ h_base,             // 3 * B*H bf16 (zeroed), u64 view
            float* __restrict__ out,              // B*T f32
            unsigned* __restrict__ bars) {        // BG_ x 64 per-wave flags
  __shared__ __align__(16) u64   h_lds[32 * 128];  // 32 rows x 64 16B chunks, xor-swizzled
  __shared__ __align__(16) float gbuf[32][GSTR];   // gates staging
  __shared__ __align__(16) float bias_s[128];
  __shared__ float wout_s[H_];

  const int tid = threadIdx.x;
  const int wg  = blockIdx.x;
  const int bg  = wg >> 4;            // 0..3
  const int g   = wg & (WPG_ - 1);    // 0..15
  const int j0g = g * JW_;

  const int wv   = tid >> 6;          // wave = gate type 0..3
  const int lane = tid & 63;
  const int m16  = lane & 15;
  const int q    = lane >> 4;
  const int sw   = m16 & 7;           // xor-swizzle key

  // ---- one-time: W fragments -> registers (B operand, 2 N-tiles x 20 K) --
  s8v bfrag[2][20];
#pragma unroll
  for (int nt = 0; nt < 2; ++nt) {
    const int r = wv * H_ + j0g + nt * 16 + m16;        // global gate row
    const float* wih_r = W_ih + (size_t)r * E_;
    const float* whh_r = W_hh + (size_t)r * H_;
#pragma unroll
    for (int ks = 0; ks < 20; ++ks) {
      s8v v;
#pragma unroll
      for (int i = 0; i < 8; ++i) {
        int k = ks * 32 + q * 8 + i;
        float w = (k < E_) ? wih_r[k] : whh_r[k - E_];
        __hip_bfloat16 hb = __float2bfloat16(w);
        v[i] = *(short*)&hb;
      }
      bfrag[nt][ks] = v;
    }
  }
  if (tid < 128) {
    int gt = tid >> 5, jl = tid & 31;
    int r = gt * H_ + j0g + jl;
    bias_s[tid] = b_ih[r] + b_hh[r];
  }
  if (g == 0) for (int i = tid; i < H_; i += 256) wout_s[i] = W_out[i];

  // ---- per-step identities ----------------------------------------------
  const int um = tid >> 3;            // update/out/fill row
  const int jb = (tid & 7) * 4;       // update: 4 hidden units
  const int ub = bg * 32 + um;
  const int fc = tid & 7;             // fill: chunk base
  float cst[4] = {0.f, 0.f, 0.f, 0.f};
  const float bout = b_out[0];
  unsigned* flags  = bars + bg * 64;  // 64 per-wave flags (256B)
  unsigned* myflag = flags + (g << 2) + wv;

  int rp = 2, wp = 0;                 // h_{-1}=zeros in buf2; h_t -> buf[t%3]
  f4v acc[2][2];

  // prologue: x-part of step 0
  {
    const __hip_bfloat16* ax0 = x_bf + (size_t)(bg * 32 + m16) * E_ + q * 8;
    const __hip_bfloat16* ax1 = x_bf + (size_t)(bg * 32 + 16 + m16) * E_ + q * 8;
    f4v z = {0.f, 0.f, 0.f, 0.f};
    acc[0][0] = z; acc[0][1] = z; acc[1][0] = z; acc[1][1] = z;
#pragma unroll
    for (int ks = 0; ks < 4; ++ks) {
      s8v a0 = *(const s8v*)(ax0 + ks * 32);
      s8v a1 = *(const s8v*)(ax1 + ks * 32);
#pragma unroll
      for (int nt = 0; nt < 2; ++nt) {
        acc[0][nt] = __builtin_amdgcn_mfma_f32_16x16x32_bf16(a0, bfrag[nt][ks], acc[0][nt], 0, 0, 0);
        acc[1][nt] = __builtin_amdgcn_mfma_f32_16x16x32_bf16(a1, bfrag[nt][ks], acc[1][nt], 0, 0, 0);
      }
    }
  }
  __syncthreads();   // bias/wout ready

  for (int t = 0; t < T_; ++t) {
    const u64* h_prev = h_base + (size_t)rp * HU64_;
    u64*       h_next = h_base + (size_t)wp * HU64_;

    // ---- wave 0 polls for step t-1 producers; barrier releases the WG ---
    if (wv == 0) wait_flags64(flags, (unsigned)t);
    __syncthreads();   // release; also orders shadow h_lds reads before fill

    // ---- cooperative fill: h_{t-1} slab -> LDS (xor-swizzled chunks) ----
    {
      const u64* src = h_prev + (size_t)(bg * 32 + um) * 128;
      u64 v[16];
#pragma unroll
      for (int j = 0; j < 8; ++j) {
        int lc = fc + 8 * j;
        v[2 * j]     = llc_load8(src + lc * 2);
        v[2 * j + 1] = llc_load8(src + lc * 2 + 1);
      }
      u64* dst = h_lds + (size_t)um * 128;
#pragma unroll
      for (int j = 0; j < 8; ++j) {
        int pc = ((fc + 8 * j) ^ (um & 7)) * 2;
        dst[pc]     = v[2 * j];
        dst[pc + 1] = v[2 * j + 1];
      }
    }
    __syncthreads();   // fill complete

    // ---- h-part MFMAs (K=512 from LDS; B from registers) ----------------
    {
      const u64* al0 = h_lds + (size_t)m16 * 128;
      const u64* al1 = h_lds + (size_t)(16 + m16) * 128;
#pragma unroll
      for (int ks4 = 0; ks4 < 16; ++ks4) {
        int pc = ((ks4 * 4 + q) ^ sw) * 2;
        s8v a0 = *(const s8v*)(al0 + pc);
        s8v a1 = *(const s8v*)(al1 + pc);
#pragma unroll
        for (int nt = 0; nt < 2; ++nt) {
          acc[0][nt] = __builtin_amdgcn_mfma_f32_16x16x32_bf16(a0, bfrag[nt][4 + ks4], acc[0][nt], 0, 0, 0);
          acc[1][nt] = __builtin_amdgcn_mfma_f32_16x16x32_bf16(a1, bfrag[nt][4 + ks4], acc[1][nt], 0, 0, 0);
        }
      }
    }

    // ---- stage gates to LDS (D: row=quad*4+r, col=m16) ------------------
#pragma unroll
    for (int mt = 0; mt < 2; ++mt)
#pragma unroll
      for (int nt = 0; nt < 2; ++nt)
#pragma unroll
        for (int r = 0; r < 4; ++r)
          gbuf[mt * 16 + q * 4 + r][wv * 32 + nt * 16 + m16] = acc[mt][nt][r];
    __syncthreads();   // gates ready

    // ---- CRITICAL PATH: pointwise -> h store -> drain -> flag -----------
    {
      const float* gr = &gbuf[0][0] + (size_t)um * GSTR;
      f4v vi = *(const f4v*)(gr + jb);
      f4v vf = *(const f4v*)(gr + 32 + jb);
      f4v vg = *(const f4v*)(gr + 64 + jb);
      f4v vo = *(const f4v*)(gr + 96 + jb);
      f4v bi = *(const f4v*)(bias_s + jb);
      f4v bf = *(const f4v*)(bias_s + 32 + jb);
      f4v bgc = *(const f4v*)(bias_s + 64 + jb);
      f4v bo = *(const f4v*)(bias_s + 96 + jb);
      u64 packed = 0;
#pragma unroll
      for (int qq = 0; qq < 4; ++qq) {
        float si = sigf(vi[qq] + bi[qq]);
        float sf = sigf(vf[qq] + bf[qq]);
        float tg = tanh_f(vg[qq] + bgc[qq]);
        float so = sigf(vo[qq] + bo[qq]);
        cst[qq] = sf * cst[qq] + si * tg;
        float h = so * tanh_f(cst[qq]);
        __hip_bfloat16 hb = __float2bfloat16(h);
        packed |= (u64)(*(unsigned short*)&hb) << (16 * qq);
      }
      llc_store8(h_next + (size_t)ub * 128 + ((j0g + jb) >> 2), packed);
    }
    // per-wave: drain own sc1 stores (acked at LLC), then publish wave flag
    asm volatile("s_waitcnt vmcnt(0)" ::: "memory");
    if (lane == 0) llc_store4(myflag, (unsigned)(t + 1));

    // ---- poll-shadow work (other WGs are polling/filling) ---------------
    if (g == 0 && t > 0)               // h_{t-1} still staged in LDS
      out_dot_lds(h_lds, t - 1, bg, wout_s, bout, out);

    if (t + 1 < T_) {                  // x-part of step t+1
      const __hip_bfloat16* xt = x_bf + (size_t)(t + 1) * B_ * E_;
      const __hip_bfloat16* ax0 = xt + (size_t)(bg * 32 + m16) * E_ + q * 8;
      const __hip_bfloat16* ax1 = xt + (size_t)(bg * 32 + 16 + m16) * E_ + q * 8;
      f4v z = {0.f, 0.f, 0.f, 0.f};
      acc[0][0] = z; acc[0][1] = z; acc[1][0] = z; acc[1][1] = z;
#pragma unroll
      for (int ks = 0; ks < 4; ++ks) {
        s8v a0 = *(const s8v*)(ax0 + ks * 32);
        s8v a1 = *(const s8v*)(ax1 + ks * 32);
#pragma unroll
        for (int nt = 0; nt < 2; ++nt) {
          acc[0][nt] = __builtin_amdgcn_mfma_f32_16x16x32_bf16(a0, bfrag[nt][ks], acc[0][nt], 0, 0, 0);
          acc[1][nt] = __builtin_amdgcn_mfma_f32_16x16x32_bf16(a1, bfrag[nt][ks], acc[1][nt], 0, 0, 0);
        }
      }
    }
    // no tail sync: the loop-head barrier protects h_lds/gbuf reuse

    rp = wp; wp = (wp == 2) ? 0 : wp + 1;
  }

  // final output row: h_{T-1} from global (rp buffer after last rotation)
  if (g == 0) {
    if (wv == 0) wait_flags64(flags, (unsigned)T_);
    __syncthreads();
    out_dot_glb(h_base + (size_t)rp * HU64_, T_ - 1, bg, wout_s, bout, out);
  }
}

// ---------------------------------------------------------------------------
extern "C" void kernel_launch(void* const* d_in, const int* in_sizes, int n_in,
                              void* d_out, int out_size, void* d_ws, size_t ws_size,
                              hipStream_t stream) {
  const int*   tokens = (const int*)d_in[0];
  const float* values = (const float*)d_in[1];
  const float* emb    = (const float*)d_in[2];
  const float* W_ih   = (const float*)d_in[3];
  const float* W_hh   = (const float*)d_in[4];
  const float* b_ih   = (const float*)d_in[5];
  const float* b_hh   = (const float*)d_in[6];
  const float* W_out  = (const float*)d_in[7];
  const float* b_out  = (const float*)d_in[8];
  float* out = (float*)d_out;

  char* ws = (char*)d_ws;
  __hip_bfloat16* x_bf = (__hip_bfloat16*)ws;                         // 16 MB
  u64* h_base = (u64*)(ws + (size_t)T_ * B_ * E_ * 2);                // 3 * 128KB
  unsigned* bars = (unsigned*)(ws + (size_t)T_ * B_ * E_ * 2
                                  + (size_t)3 * HU64_ * sizeof(u64)); // 1 KB

  hipMemsetAsync(h_base, 0, (size_t)3 * HU64_ * sizeof(u64), stream);
  hipMemsetAsync(bars, 0, (size_t)BG_ * 64 * sizeof(unsigned), stream);

  embed_kernel<<<(B_ * T_ * E_) / 256, 256, 0, stream>>>(tokens, values, emb, x_bf);

  lstm_kernel<<<dim3(BG_ * WPG_), dim3(256), 0, stream>>>(
      W_ih, W_hh, b_ih, b_hh, W_out, b_out, x_bf, h_base, out, bars);
}